// Round 4
// baseline (782.900 us; speedup 1.0000x reference)
//
#include <hip/hip_runtime.h>
#include <hip/hip_bf16.h>

// Problem constants (fixed by setup_inputs):
#define BB 4
#define PP 32
#define TT 128
#define CC 16
#define TCC 64
#define HH 256
#define NHH 8
#define DD 32      // HH / NHH
#define FFF 1024
// gat_iter=2, padding_idx=0, n_heads=8 hard-coded.
// Inputs: fp32 (proven round1 NaN vs round2 finite). Output: fp32 (round-3
// 0.611 signature == bf16-packed context leaking into fp32 slot window).

typedef __hip_bfloat16 bf16;

// Scratch in module __device__ globals (no d_ws dependence). Every buffer is
// fully written before read on every launch.
__device__ float g_para_feat [BB * PP * HH];
__device__ float g_clus_feat [BB * CC * HH];
__device__ float g_para_state[BB * PP * HH];
__device__ float g_clus_state[BB * CC * HH];
__device__ float g_qb        [BB * PP * HH];
__device__ float g_kb        [BB * PP * HH];
__device__ float g_vb        [BB * PP * HH];
__device__ int   g_flag;

// Defensive dtype probe (expected: fp32 -> g_flag=0).
template<typename WT> __device__ __forceinline__ float ldw(const void* p, size_t i);
template<> __device__ __forceinline__ float ldw<float>(const void* p, size_t i) {
    return ((const float*)p)[i];
}
template<> __device__ __forceinline__ float ldw<bf16>(const void* p, size_t i) {
    return __bfloat162float(((const bf16*)p)[i]);
}

__global__ void k_probe(const unsigned* __restrict__ lng) {
    // ff_ln_g is all-ones: fp32 word0 = 0x3F800000 ; bf16 pair = 0x3F803F80
    g_flag = (lng[0] == 0x3F803F80u) ? 1 : 0;
}

// ---------------------------------------------------------------------------
// Encode: masked mean-pool of token embeddings.
// ---------------------------------------------------------------------------
template<typename WT>
__device__ void encode_body(const int* __restrict__ src, const int* __restrict__ cluster,
                            const void* __restrict__ emb) {
    int bid = blockIdx.x, tid = threadIdx.x;
    if (bid < BB * PP) {
        const int* toks = src + bid * TT;
        float acc = 0.f; int cnt = 0;
        for (int i = 0; i < TT; i++) {
            int tk = toks[i];
            if (tk != 0) { cnt++; acc += ldw<WT>(emb, (size_t)tk * HH + tid); }
        }
        g_para_feat[bid * HH + tid] = acc / fmaxf((float)cnt, 1.0f);
    } else {
        int cid = bid - BB * PP;
        const int* toks = cluster + cid * TCC;
        float acc = 0.f; int cnt = 0;
        for (int i = 0; i < TCC; i++) {
            int tk = toks[i];
            if (tk != 0) { cnt++; acc += ldw<WT>(emb, (size_t)tk * HH + tid); }
        }
        g_clus_feat[cid * HH + tid] = acc / fmaxf((float)cnt, 1.0f);
    }
}

__global__ void k_encode(const int* src, const int* cluster, const void* emb) {
    if (g_flag) encode_body<bf16>(src, cluster, emb);
    else        encode_body<float>(src, cluster, emb);
}

// ---------------------------------------------------------------------------
// GAT q/k/v projection into g_qb/g_kb/g_vb.
// grid: (max(rows_q, rows_k), 3), 256 threads (thread = output col)
// ---------------------------------------------------------------------------
template<typename WT>
__device__ void proj_body(const float* __restrict__ qsrc, const float* __restrict__ kvsrc,
                          int rows_q, int rows_k,
                          const void* __restrict__ wq, const void* __restrict__ wk,
                          const void* __restrict__ wv) {
    int r = blockIdx.x, which = blockIdx.y, tid = threadIdx.x;
    const float* src; const void* w; float* dst; int rows;
    if (which == 0)      { src = qsrc;  w = wq; dst = g_qb; rows = rows_q; }
    else if (which == 1) { src = kvsrc; w = wk; dst = g_kb; rows = rows_k; }
    else                 { src = kvsrc; w = wv; dst = g_vb; rows = rows_k; }
    if (r >= rows) return;
    __shared__ float xs[HH];
    xs[tid] = src[r * HH + tid];
    __syncthreads();
    float acc = 0.f;
    for (int i = 0; i < HH; i++) acc += xs[i] * ldw<WT>(w, i * HH + tid);
    dst[r * HH + tid] = acc;
}

__global__ void k_proj(const float* qsrc, const float* kvsrc, int rows_q, int rows_k,
                       const void* wq, const void* wk, const void* wv) {
    if (g_flag) proj_body<bf16>(qsrc, kvsrc, rows_q, rows_k, wq, wk, wv);
    else        proj_body<float>(qsrc, kvsrc, rows_q, rows_k, wq, wk, wv);
}

// ---------------------------------------------------------------------------
// GAT attention + output projection + residual. One block per (b, q_node).
// p2c=1: q=para (Nq=32), kv=cluster (Nk=16), mask[b,qi,kk]=edge[b,qi,kk]>0
// p2c=0: q=cluster (Nq=16), kv=para (Nk=32), mask[b,qi,kk]=edge[b,kk,qi]>0
// ---------------------------------------------------------------------------
template<typename WT>
__device__ void attn_body(const float* __restrict__ qn,
                          const int* __restrict__ edge, const void* __restrict__ wo,
                          float* __restrict__ dst, int Nq, int Nk, int p2c) {
    int r = blockIdx.x, tid = threadIdx.x;
    int b = r / Nq, qi = r % Nq;
    __shared__ float q_s[HH];
    __shared__ float o_s[HH];
    __shared__ float p_s[NHH][32];
    __shared__ float ssum[NHH];
    __shared__ int   msk[32];
    __shared__ int   hasnb;

    q_s[tid] = g_qb[r * HH + tid];
    if (tid < Nk) {
        int e = p2c ? edge[(b * PP + qi) * CC + tid]
                    : edge[(b * PP + tid) * CC + qi];
        msk[tid] = (e > 0) ? 1 : 0;
    }
    __syncthreads();

    int h = tid >> 5, kk = tid & 31;
    float sc = -1e9f;
    if (kk < Nk) {
        const float* krow = g_kb + (size_t)(b * Nk + kk) * HH + h * DD;
        float acc = 0.f;
        #pragma unroll
        for (int d2 = 0; d2 < DD; d2++) acc += q_s[h * DD + d2] * krow[d2];
        sc = msk[kk] ? acc * 0.17677669529663687f : -1e9f;  // 1/sqrt(32)
    }
    p_s[h][kk] = sc;
    __syncthreads();

    if (tid < NHH) {
        float mx = -1e30f;
        for (int k2 = 0; k2 < Nk; k2++) mx = fmaxf(mx, p_s[tid][k2]);
        float sm = 0.f;
        for (int k2 = 0; k2 < Nk; k2++) {
            float e2 = __expf(p_s[tid][k2] - mx);
            p_s[tid][k2] = e2; sm += e2;
        }
        ssum[tid] = sm;
    }
    if (tid == 0) {
        int a = 0;
        for (int k2 = 0; k2 < Nk; k2++) a |= msk[k2];
        hasnb = a;
    }
    __syncthreads();

    {   // o[h*32+dd] = (1/ssum) * sum_k p[h][k] * v[b,k,h,dd]
        float inv = 1.f / ssum[h];
        float o = 0.f;
        for (int k2 = 0; k2 < Nk; k2++)
            o += p_s[h][k2] * g_vb[(size_t)(b * Nk + k2) * HH + h * DD + kk];
        o_s[tid] = o * inv;
    }
    __syncthreads();

    float acc = 0.f;
    for (int i = 0; i < HH; i++) acc += o_s[i] * ldw<WT>(wo, i * HH + tid);
    float res = qn[r * HH + tid] + (hasnb ? acc : 0.f);
    dst[r * HH + tid] = res;   // in-place safe: row r owned by this block
}

__global__ void k_attn(const float* qn, const int* edge, const void* wo,
                       float* dst, int Nq, int Nk, int p2c) {
    if (g_flag) attn_body<bf16>(qn, edge, wo, dst, Nq, Nk, p2c);
    else        attn_body<float>(qn, edge, wo, dst, Nq, Nk, p2c);
}

// ---------------------------------------------------------------------------
// Write para_state / cluster_state sections of d_out (fp32)
// ---------------------------------------------------------------------------
__global__ void k_states_out(float* __restrict__ out) {
    int i = blockIdx.x * 256 + threadIdx.x;
    if (i < BB * PP * HH) {
        out[i] = g_para_state[i];
    } else {
        int j = i - BB * PP * HH;
        out[(size_t)BB * PP * HH + (size_t)BB * PP * TT * HH + j] = g_clus_state[j];
    }
}

// ---------------------------------------------------------------------------
// FFN over all B*P*T tokens. 8 tokens per block, 256 threads.
// ---------------------------------------------------------------------------
#define TM 8
template<typename WT>
__device__ void ffn_body(const int* __restrict__ src, const void* __restrict__ emb,
                         const void* __restrict__ w1, const void* __restrict__ b1,
                         const void* __restrict__ w2, const void* __restrict__ b2,
                         const void* __restrict__ lng, const void* __restrict__ lnb,
                         float* __restrict__ out_ctx) {
    int tid = threadIdx.x;
    int t0 = blockIdx.x * TM;          // flat token index over [B*P*T]
    __shared__ float xs[TM][HH];       // residual x
    __shared__ float xn[TM][HH];       // layernorm(x)
    __shared__ float hs[TM][FFF];      // hidden (32 KB)
    __shared__ float mu[TM], rs[TM];
    __shared__ int   toks[TM];

    if (tid < TM) toks[tid] = src[t0 + tid];
    __syncthreads();

    #pragma unroll
    for (int m = 0; m < TM; m++) {
        int tk = toks[m];
        int pr = (t0 + m) >> 7;        // /TT -> flat (b*P+p)
        float e = (tk != 0) ? ldw<WT>(emb, (size_t)tk * HH + tid) : 0.f;
        xs[m][tid] = e + g_para_state[pr * HH + tid];
    }
    __syncthreads();

    {   // LN stats: 8 groups of 32 lanes, one token each
        int m = tid >> 5, ln = tid & 31;
        float s = 0.f, s2 = 0.f;
        #pragma unroll
        for (int i = ln; i < HH; i += 32) { float v = xs[m][i]; s += v; s2 += v * v; }
        #pragma unroll
        for (int off = 16; off > 0; off >>= 1) {
            s  += __shfl_down(s,  off, 32);
            s2 += __shfl_down(s2, off, 32);
        }
        if (ln == 0) {
            float mean = s * (1.f / HH);
            float var  = s2 * (1.f / HH) - mean * mean;
            mu[m] = mean; rs[m] = rsqrtf(var + 1e-6f);
        }
    }
    __syncthreads();
    {
        float g = ldw<WT>(lng, tid), bt = ldw<WT>(lnb, tid);
        #pragma unroll
        for (int m = 0; m < TM; m++) xn[m][tid] = (xs[m][tid] - mu[m]) * rs[m] * g + bt;
    }
    __syncthreads();

    // h = relu(xn @ W1 + b1): thread owns cols {tid, tid+256, tid+512, tid+768}
    float acc[4][TM];
    #pragma unroll
    for (int jj = 0; jj < 4; jj++)
        #pragma unroll
        for (int m = 0; m < TM; m++) acc[jj][m] = 0.f;
    for (int i = 0; i < HH; i++) {
        float wv0 = ldw<WT>(w1, i * FFF + tid);
        float wv1 = ldw<WT>(w1, i * FFF + tid + 256);
        float wv2 = ldw<WT>(w1, i * FFF + tid + 512);
        float wv3 = ldw<WT>(w1, i * FFF + tid + 768);
        #pragma unroll
        for (int m = 0; m < TM; m++) {
            float xv = xn[m][i];
            acc[0][m] += xv * wv0; acc[1][m] += xv * wv1;
            acc[2][m] += xv * wv2; acc[3][m] += xv * wv3;
        }
    }
    #pragma unroll
    for (int jj = 0; jj < 4; jj++) {
        float bb = ldw<WT>(b1, tid + jj * 256);
        #pragma unroll
        for (int m = 0; m < TM; m++) hs[m][tid + jj * 256] = fmaxf(acc[jj][m] + bb, 0.f);
    }
    __syncthreads();

    // out = h @ W2 + b2 + x, masked, fp32
    float acc2[TM];
    #pragma unroll
    for (int m = 0; m < TM; m++) acc2[m] = 0.f;
    for (int i = 0; i < FFF; i++) {
        float wv = ldw<WT>(w2, i * HH + tid);
        #pragma unroll
        for (int m = 0; m < TM; m++) acc2[m] += hs[m][i] * wv;
    }
    float bb = ldw<WT>(b2, tid);
    #pragma unroll
    for (int m = 0; m < TM; m++) {
        float v = (toks[m] != 0) ? (acc2[m] + bb + xs[m][tid]) : 0.f;
        out_ctx[(size_t)(t0 + m) * HH + tid] = v;
    }
}

__global__ void __launch_bounds__(256) k_ffn(
        const int* src, const void* emb,
        const void* w1, const void* b1, const void* w2, const void* b2,
        const void* lng, const void* lnb, float* out_ctx) {
    if (g_flag) ffn_body<bf16>(src, emb, w1, b1, w2, b2, lng, lnb, out_ctx);
    else        ffn_body<float>(src, emb, w1, b1, w2, b2, lng, lnb, out_ctx);
}

// ---------------------------------------------------------------------------
extern "C" void kernel_launch(void* const* d_in, const int* in_sizes, int n_in,
                              void* d_out, int out_size, void* d_ws, size_t ws_size,
                              hipStream_t stream) {
    const int*  src     = (const int*)d_in[0];
    const int*  cluster = (const int*)d_in[1];
    const int*  edge    = (const int*)d_in[2];
    const void* emb     = d_in[3];
    const void* p2c_wq  = d_in[4];
    const void* p2c_wk  = d_in[5];
    const void* p2c_wv  = d_in[6];
    const void* p2c_wo  = d_in[7];
    const void* c2p_wq  = d_in[8];
    const void* c2p_wk  = d_in[9];
    const void* c2p_wv  = d_in[10];
    const void* c2p_wo  = d_in[11];
    const void* w1      = d_in[12];
    const void* b1      = d_in[13];
    const void* w2      = d_in[14];
    const void* b2p     = d_in[15];
    const void* lng     = d_in[16];
    const void* lnb     = d_in[17];
    // d_in[18..20]: gat_iter=2, padding_idx=0, n_heads=8 (hard-coded)

    float *para_feat, *clus_feat, *para_state, *clus_state;
    hipGetSymbolAddress((void**)&para_feat,  HIP_SYMBOL(g_para_feat));
    hipGetSymbolAddress((void**)&clus_feat,  HIP_SYMBOL(g_clus_feat));
    hipGetSymbolAddress((void**)&para_state, HIP_SYMBOL(g_para_state));
    hipGetSymbolAddress((void**)&clus_state, HIP_SYMBOL(g_clus_state));

    float* out     = (float*)d_out;
    float* out_ctx = out + BB * PP * HH;           // para_context section

    k_probe<<<dim3(1), dim3(1), 0, stream>>>((const unsigned*)lng);
    k_encode<<<dim3(192), dim3(256), 0, stream>>>(src, cluster, emb);

    auto gat = [&](const float* qsrc, const float* kvsrc, float* dst,
                   const void* wq, const void* wk, const void* wv, const void* wo,
                   int Nq, int Nk, int p2c) {
        int rq = BB * Nq, rk = BB * Nk;
        int gx = rq > rk ? rq : rk;
        k_proj<<<dim3(gx, 3), dim3(256), 0, stream>>>(qsrc, kvsrc, rq, rk, wq, wk, wv);
        k_attn<<<dim3(rq), dim3(256), 0, stream>>>(qsrc, edge, wo, dst, Nq, Nk, p2c);
    };

    // para_state = GAT_p2c(para_feat, clus_feat)
    gat(para_feat,  clus_feat,  para_state, p2c_wq, p2c_wk, p2c_wv, p2c_wo, PP, CC, 1);
    // 2 iterations of (c2p, p2c); initial cluster_state = clus_feat
    gat(clus_feat,  para_state, clus_state, c2p_wq, c2p_wk, c2p_wv, c2p_wo, CC, PP, 0);
    gat(para_state, clus_state, para_state, p2c_wq, p2c_wk, p2c_wv, p2c_wo, PP, CC, 1);
    gat(clus_state, para_state, clus_state, c2p_wq, c2p_wk, c2p_wv, c2p_wo, CC, PP, 0);
    gat(para_state, clus_state, para_state, p2c_wq, p2c_wk, p2c_wv, p2c_wo, PP, CC, 1);

    k_states_out<<<dim3(192), dim3(256), 0, stream>>>(out);
    k_ffn<<<dim3(2048), dim3(256), 0, stream>>>(src, emb,
                                                w1, b1, w2, b2p, lng, lnb, out_ctx);
}

// Round 5
// 532.588 us; speedup vs baseline: 1.4700x; 1.4700x over previous
//
#include <hip/hip_runtime.h>
#include <hip/hip_bf16.h>

// Problem constants (fixed by setup_inputs):
#define BB 4
#define PP 32
#define TT 128
#define CC 16
#define TCC 64
#define HH 256
#define NHH 8
#define DD 32      // HH / NHH
#define FFF 1024
// gat_iter=2, padding_idx=0, n_heads=8 hard-coded.
// Inputs fp32, output fp32 (established rounds 0-4; round 4 passed).

typedef __hip_bfloat16 bf16;
typedef __attribute__((ext_vector_type(8))) short bh8;    // 8 bf16 (4 VGPRs)
typedef __attribute__((ext_vector_type(4))) float f32x4;  // MFMA C/D

// Scratch in device globals (fully rewritten before read every launch).
__device__ float g_para_feat [BB * PP * HH];
__device__ float g_clus_feat [BB * CC * HH];
__device__ float g_para_state[BB * PP * HH];
__device__ float g_clus_state[BB * CC * HH];
__device__ float g_qb        [BB * PP * HH];
__device__ float g_kb        [BB * PP * HH];
__device__ float g_vb        [BB * PP * HH];
// Fragment-packed bf16 weights for the FFN MFMA kernel:
// g_w1p: [ntile(64)][kstep(8)][lane(64)][j(8)]  w1[k= kstep*32+quad*8+j][n= ntile*16+col]
// g_w2p: [ntile(16)][kstep(32)][lane(64)][j(8)] w2[k][n] same mapping
__device__ short g_w1p[HH * FFF];
__device__ short g_w2p[FFF * HH];

__device__ __forceinline__ short f2b(float f) {
    union { __hip_bfloat16 h; short s; } u;
    u.h = __float2bfloat16(f);
    return u.s;
}

// ---------------------------------------------------------------------------
// Pack W1/W2 (fp32) into MFMA B-fragment order (bf16 bits). 65536 threads.
// ---------------------------------------------------------------------------
__global__ void k_pack(const float* __restrict__ w1, const float* __restrict__ w2) {
    int idx = blockIdx.x * 256 + threadIdx.x;
    int lane = idx & 63, quad = (idx >> 4) & 3, col = idx & 15;
    if (idx < 32768) {                       // W1 frags
        int rest = idx >> 6;
        int kstep = rest & 7, ntile = rest >> 3;
        short* dst = g_w1p + (size_t)idx * 8;
        #pragma unroll
        for (int j = 0; j < 8; j++)
            dst[j] = f2b(w1[(kstep * 32 + quad * 8 + j) * FFF + ntile * 16 + col]);
    } else {                                 // W2 frags
        int id2 = idx - 32768;
        int rest = id2 >> 6;
        int kstep = rest & 31, ntile = rest >> 5;
        short* dst = g_w2p + (size_t)id2 * 8;
        #pragma unroll
        for (int j = 0; j < 8; j++)
            dst[j] = f2b(w2[(kstep * 32 + quad * 8 + j) * HH + ntile * 16 + col]);
    }
    (void)lane;
}

// ---------------------------------------------------------------------------
// Encode: masked mean-pool of token embeddings.
// ---------------------------------------------------------------------------
__global__ void k_encode(const int* __restrict__ src, const int* __restrict__ cluster,
                         const float* __restrict__ emb) {
    int bid = blockIdx.x, tid = threadIdx.x;
    if (bid < BB * PP) {
        const int* toks = src + bid * TT;
        float acc = 0.f; int cnt = 0;
        for (int i = 0; i < TT; i++) {
            int tk = toks[i];
            if (tk != 0) { cnt++; acc += emb[(size_t)tk * HH + tid]; }
        }
        g_para_feat[bid * HH + tid] = acc / fmaxf((float)cnt, 1.0f);
    } else {
        int cid = bid - BB * PP;
        const int* toks = cluster + cid * TCC;
        float acc = 0.f; int cnt = 0;
        for (int i = 0; i < TCC; i++) {
            int tk = toks[i];
            if (tk != 0) { cnt++; acc += emb[(size_t)tk * HH + tid]; }
        }
        g_clus_feat[cid * HH + tid] = acc / fmaxf((float)cnt, 1.0f);
    }
}

// ---------------------------------------------------------------------------
// GAT q/k/v projection into g_qb/g_kb/g_vb.
// ---------------------------------------------------------------------------
__global__ void k_proj(const float* __restrict__ qsrc, const float* __restrict__ kvsrc,
                       int rows_q, int rows_k,
                       const float* __restrict__ wq, const float* __restrict__ wk,
                       const float* __restrict__ wv) {
    int r = blockIdx.x, which = blockIdx.y, tid = threadIdx.x;
    const float* src; const float* w; float* dst; int rows;
    if (which == 0)      { src = qsrc;  w = wq; dst = g_qb; rows = rows_q; }
    else if (which == 1) { src = kvsrc; w = wk; dst = g_kb; rows = rows_k; }
    else                 { src = kvsrc; w = wv; dst = g_vb; rows = rows_k; }
    if (r >= rows) return;
    __shared__ float xs[HH];
    xs[tid] = src[r * HH + tid];
    __syncthreads();
    float acc = 0.f;
    for (int i = 0; i < HH; i++) acc += xs[i] * w[i * HH + tid];
    dst[r * HH + tid] = acc;
}

// ---------------------------------------------------------------------------
// GAT attention + output projection + residual. One block per (b, q_node).
// out2 != nullptr -> also write result to that fp32 output section.
// ---------------------------------------------------------------------------
__global__ void k_attn(const float* __restrict__ qn, const int* __restrict__ edge,
                       const float* __restrict__ wo, float* __restrict__ dst,
                       float* __restrict__ out2, int Nq, int Nk, int p2c) {
    int r = blockIdx.x, tid = threadIdx.x;
    int b = r / Nq, qi = r % Nq;
    __shared__ float q_s[HH];
    __shared__ float o_s[HH];
    __shared__ float p_s[NHH][32];
    __shared__ float ssum[NHH];
    __shared__ int   msk[32];
    __shared__ int   hasnb;

    q_s[tid] = g_qb[r * HH + tid];
    if (tid < Nk) {
        int e = p2c ? edge[(b * PP + qi) * CC + tid]
                    : edge[(b * PP + tid) * CC + qi];
        msk[tid] = (e > 0) ? 1 : 0;
    }
    __syncthreads();

    int h = tid >> 5, kk = tid & 31;
    float sc = -1e9f;
    if (kk < Nk) {
        const float* krow = g_kb + (size_t)(b * Nk + kk) * HH + h * DD;
        float acc = 0.f;
        #pragma unroll
        for (int d2 = 0; d2 < DD; d2++) acc += q_s[h * DD + d2] * krow[d2];
        sc = msk[kk] ? acc * 0.17677669529663687f : -1e9f;  // 1/sqrt(32)
    }
    p_s[h][kk] = sc;
    __syncthreads();

    if (tid < NHH) {
        float mx = -1e30f;
        for (int k2 = 0; k2 < Nk; k2++) mx = fmaxf(mx, p_s[tid][k2]);
        float sm = 0.f;
        for (int k2 = 0; k2 < Nk; k2++) {
            float e2 = __expf(p_s[tid][k2] - mx);
            p_s[tid][k2] = e2; sm += e2;
        }
        ssum[tid] = sm;
    }
    if (tid == 0) {
        int a = 0;
        for (int k2 = 0; k2 < Nk; k2++) a |= msk[k2];
        hasnb = a;
    }
    __syncthreads();

    {
        float inv = 1.f / ssum[h];
        float o = 0.f;
        for (int k2 = 0; k2 < Nk; k2++)
            o += p_s[h][k2] * g_vb[(size_t)(b * Nk + k2) * HH + h * DD + kk];
        o_s[tid] = o * inv;
    }
    __syncthreads();

    float acc = 0.f;
    for (int i = 0; i < HH; i++) acc += o_s[i] * wo[i * HH + tid];
    float res = qn[r * HH + tid] + (hasnb ? acc : 0.f);
    dst[r * HH + tid] = res;
    if (out2) out2[r * HH + tid] = res;
}

// ---------------------------------------------------------------------------
// Fused FFN, bf16 MFMA. 64 tokens/block (4 waves x 16-row strips), grid=256.
// mfma_f32_16x16x32_bf16: A[m=lane&15][k=quad*8+j], B[k=quad*8+j][n=lane&15],
// C/D[row=quad*4+reg][col=lane&15].
// ---------------------------------------------------------------------------
__global__ void __launch_bounds__(256) k_ffn_mfma(
        const int* __restrict__ src, const float* __restrict__ emb,
        const float* __restrict__ b1, const float* __restrict__ b2v,
        const float* __restrict__ lng, const float* __restrict__ lnb,
        float* __restrict__ out_ctx) {
    __shared__ short xn[64][264];          // LN output, bf16 bits (+8 pad: bank spread)
    __shared__ short sbuf[4][16][136];     // per-wave hidden chunk (C->A roundtrip)
    __shared__ float red_s[64][4], red_s2[64][4];
    __shared__ float mu[64], rsd[64];
    __shared__ int   toks[64];

    int tid = threadIdx.x;
    int t0 = blockIdx.x * 64;

    if (tid < 64) toks[tid] = src[t0 + tid];
    __syncthreads();

    {   // LN stats: thread (m=tid>>2, q=tid&3) sums a 64-dim quarter
        int m = tid >> 2, q = tid & 3;
        int tk = toks[m];
        const float* er = emb + (size_t)tk * HH;
        const float* pp = g_para_state + ((t0 + m) >> 7) * HH;
        float s = 0.f, s2 = 0.f;
        for (int j = 0; j < 64; j++) {
            int d = q * 64 + j;
            float x = (tk ? er[d] : 0.f) + pp[d];
            s += x; s2 += x * x;
        }
        red_s[m][q] = s; red_s2[m][q] = s2;
    }
    __syncthreads();
    if (tid < 64) {
        float s  = red_s [tid][0] + red_s [tid][1] + red_s [tid][2] + red_s [tid][3];
        float s2 = red_s2[tid][0] + red_s2[tid][1] + red_s2[tid][2] + red_s2[tid][3];
        float mean = s * (1.f / HH);
        float var  = s2 * (1.f / HH) - mean * mean;
        mu[tid] = mean; rsd[tid] = rsqrtf(var + 1e-6f);
    }
    __syncthreads();
    {   // xn: thread owns dim d=tid across all 64 tokens
        int d = tid;
        float g = lng[d], bt = lnb[d];
        for (int m = 0; m < 64; m++) {
            int tk = toks[m];
            float x = (tk ? emb[(size_t)tk * HH + d] : 0.f)
                    + g_para_state[((t0 + m) >> 7) * HH + d];
            xn[m][d] = f2b((x - mu[m]) * rsd[m] * g + bt);
        }
    }
    __syncthreads();

    int wv = tid >> 6, lane = tid & 63, quad = lane >> 4, col = lane & 15;

    f32x4 acc2[16];
    #pragma unroll
    for (int i = 0; i < 16; i++) acc2[i] = (f32x4){0.f, 0.f, 0.f, 0.f};

    for (int c = 0; c < 8; c++) {          // hidden chunk of 128 cols
        f32x4 acc1[8];
        #pragma unroll
        for (int i = 0; i < 8; i++) acc1[i] = (f32x4){0.f, 0.f, 0.f, 0.f};

        #pragma unroll
        for (int kk = 0; kk < 8; kk++) {   // K1 = 256
            bh8 a = *(const bh8*)&xn[16 * wv + col][kk * 32 + quad * 8];
            const short* wb = g_w1p + ((size_t)((c * 8 * 8 + kk) * 64 + lane)) * 8;
            #pragma unroll
            for (int nt = 0; nt < 8; nt++) {
                bh8 b = *(const bh8*)(wb + nt * 4096);   // ntile stride = 8*64*8
                acc1[nt] = __builtin_amdgcn_mfma_f32_16x16x32_bf16(a, b, acc1[nt], 0, 0, 0);
            }
        }
        // relu + bias, C-layout -> wave-private LDS (A-layout source for GEMM2)
        #pragma unroll
        for (int nt = 0; nt < 8; nt++) {
            float bias = b1[c * 128 + nt * 16 + col];
            #pragma unroll
            for (int r = 0; r < 4; r++) {
                float v = acc1[nt][r] + bias;
                sbuf[wv][quad * 4 + r][nt * 16 + col] = f2b(v > 0.f ? v : 0.f);
            }
        }
        // GEMM2 partial over this chunk's 128 K-dims (wave-local: no barrier)
        #pragma unroll
        for (int kk2 = 0; kk2 < 4; kk2++) {
            bh8 a2 = *(const bh8*)&sbuf[wv][col][kk2 * 32 + quad * 8];
            const short* wb = g_w2p + ((size_t)((c * 4 + kk2) * 64 + lane)) * 8;
            #pragma unroll
            for (int nt2 = 0; nt2 < 16; nt2++) {
                bh8 b = *(const bh8*)(wb + nt2 * 16384); // ntile stride = 32*64*8
                acc2[nt2] = __builtin_amdgcn_mfma_f32_16x16x32_bf16(a2, b, acc2[nt2], 0, 0, 0);
            }
        }
    }

    // Epilogue: + b2 + residual (recomputed fp32-exact), mask, store
    #pragma unroll
    for (int nt2 = 0; nt2 < 16; nt2++) {
        int n = nt2 * 16 + col;
        float bias = b2v[n];
        #pragma unroll
        for (int r = 0; r < 4; r++) {
            int ml = 16 * wv + quad * 4 + r;
            int gt = t0 + ml;
            int tk = toks[ml];
            float x = (tk ? emb[(size_t)tk * HH + n] : 0.f)
                    + g_para_state[(gt >> 7) * HH + n];
            float v = tk ? (acc2[nt2][r] + bias + x) : 0.f;
            out_ctx[(size_t)gt * HH + n] = v;
        }
    }
}

// ---------------------------------------------------------------------------
extern "C" void kernel_launch(void* const* d_in, const int* in_sizes, int n_in,
                              void* d_out, int out_size, void* d_ws, size_t ws_size,
                              hipStream_t stream) {
    const int*   src     = (const int*)d_in[0];
    const int*   cluster = (const int*)d_in[1];
    const int*   edge    = (const int*)d_in[2];
    const float* emb     = (const float*)d_in[3];
    const float* p2c_wq  = (const float*)d_in[4];
    const float* p2c_wk  = (const float*)d_in[5];
    const float* p2c_wv  = (const float*)d_in[6];
    const float* p2c_wo  = (const float*)d_in[7];
    const float* c2p_wq  = (const float*)d_in[8];
    const float* c2p_wk  = (const float*)d_in[9];
    const float* c2p_wv  = (const float*)d_in[10];
    const float* c2p_wo  = (const float*)d_in[11];
    const float* w1      = (const float*)d_in[12];
    const float* b1      = (const float*)d_in[13];
    const float* w2      = (const float*)d_in[14];
    const float* b2p     = (const float*)d_in[15];
    const float* lng     = (const float*)d_in[16];
    const float* lnb     = (const float*)d_in[17];
    // d_in[18..20]: gat_iter=2, padding_idx=0, n_heads=8 (hard-coded)

    float *para_feat, *clus_feat, *para_state, *clus_state;
    hipGetSymbolAddress((void**)&para_feat,  HIP_SYMBOL(g_para_feat));
    hipGetSymbolAddress((void**)&clus_feat,  HIP_SYMBOL(g_clus_feat));
    hipGetSymbolAddress((void**)&para_state, HIP_SYMBOL(g_para_state));
    hipGetSymbolAddress((void**)&clus_state, HIP_SYMBOL(g_clus_state));

    float* out      = (float*)d_out;
    float* out_ctx  = out + BB * PP * HH;                       // para_context
    float* out_clus = out + BB * PP * HH + BB * PP * TT * HH;   // cluster_state

    k_pack<<<dim3(256), dim3(256), 0, stream>>>(w1, w2);
    k_encode<<<dim3(192), dim3(256), 0, stream>>>(src, cluster, emb);

    auto gat = [&](const float* qsrc, const float* kvsrc, float* dst, float* out2,
                   const float* wq, const float* wk, const float* wv, const float* wo,
                   int Nq, int Nk, int p2c) {
        int rq = BB * Nq, rk = BB * Nk;
        int gx = rq > rk ? rq : rk;
        k_proj<<<dim3(gx, 3), dim3(256), 0, stream>>>(qsrc, kvsrc, rq, rk, wq, wk, wv);
        k_attn<<<dim3(rq), dim3(256), 0, stream>>>(qsrc, edge, wo, dst, out2, Nq, Nk, p2c);
    };

    // para_state = GAT_p2c(para_feat, clus_feat); then 2x (c2p, p2c)
    gat(para_feat,  clus_feat,  para_state, nullptr,  p2c_wq, p2c_wk, p2c_wv, p2c_wo, PP, CC, 1);
    gat(clus_feat,  para_state, clus_state, nullptr,  c2p_wq, c2p_wk, c2p_wv, c2p_wo, CC, PP, 0);
    gat(para_state, clus_state, para_state, nullptr,  p2c_wq, p2c_wk, p2c_wv, p2c_wo, PP, CC, 1);
    gat(clus_state, para_state, clus_state, out_clus, c2p_wq, c2p_wk, c2p_wv, c2p_wo, CC, PP, 0);
    gat(para_state, clus_state, para_state, out,      p2c_wq, p2c_wk, p2c_wv, p2c_wo, PP, CC, 1);

    k_ffn_mfma<<<dim3(256), dim3(256), 0, stream>>>(src, emb, b1, b2p, lng, lnb, out_ctx);
}

// Round 6
// 338.951 us; speedup vs baseline: 2.3098x; 1.5713x over previous
//
#include <hip/hip_runtime.h>
#include <hip/hip_bf16.h>

// Problem constants (fixed by setup_inputs):
#define BB 4
#define PP 32
#define TT 128
#define CC 16
#define TCC 64
#define HH 256
#define NHH 8
#define DD 32      // HH / NHH
#define FFF 1024
// gat_iter=2, padding_idx=0, n_heads=8 hard-coded.
// Inputs fp32, output fp32 (established; rounds 4-5 passed).

typedef __hip_bfloat16 bf16;
typedef __attribute__((ext_vector_type(8))) short bh8;    // 8 bf16 (4 VGPRs)
typedef __attribute__((ext_vector_type(4))) float f32x4;  // MFMA C/D

// Device-global scratch (fully rewritten before read every launch).
__device__ float g_para_feat [BB * PP * HH];
__device__ float g_clus_feat [BB * CC * HH];
__device__ float g_para_state[BB * PP * HH];
__device__ float g_clus_state[BB * CC * HH];
__device__ float g_qb        [BB * PP * HH];
__device__ float g_kb        [BB * PP * HH];
__device__ float g_vb        [BB * PP * HH];
// Chunk-contiguous fragment-packed bf16 weights (16 chunks of 64 hidden cols):
// g_w1p: [c][kk(8)][nt(4)][lane(64)][j(8)]   (16384 shorts per chunk)
// g_w2p: [c][kk2(2)][nt2(16)][lane(64)][j(8)] (16384 shorts per chunk)
__device__ __align__(16) short g_w1p[HH * FFF];
__device__ __align__(16) short g_w2p[FFF * HH];

__device__ __forceinline__ short f2b(float f) {
    union { __hip_bfloat16 h; short s; } u;
    u.h = __float2bfloat16(f);
    return u.s;
}

// ---------------------------------------------------------------------------
// k_prep: blocks [0,256): pack W1/W2 into fragment order; blocks [256,448):
// masked mean-pool encode of para/cluster features.
// ---------------------------------------------------------------------------
__global__ void __launch_bounds__(256) k_prep(
        const float* __restrict__ w1, const float* __restrict__ w2,
        const int* __restrict__ src, const int* __restrict__ cluster,
        const float* __restrict__ emb) {
    int tid = threadIdx.x;
    if (blockIdx.x < 256) {
        int idx = blockIdx.x * 256 + tid;
        int lane = idx & 63, quad = (lane >> 4) & 3, col = lane & 15;
        if (idx < 32768) {                   // W1 frags
            int f = idx >> 6;
            int nt = f & 3, kk = (f >> 2) & 7, c = f >> 5;
            short* dst = g_w1p + (size_t)idx * 8;
            int n = c * 64 + nt * 16 + col;
            #pragma unroll
            for (int j = 0; j < 8; j++)
                dst[j] = f2b(w1[(kk * 32 + quad * 8 + j) * FFF + n]);
        } else {                             // W2 frags
            int id2 = idx - 32768;
            int f = id2 >> 6;
            int nt2 = f & 15, kk2 = (f >> 4) & 1, c = f >> 5;
            short* dst = g_w2p + (size_t)id2 * 8;
            int n = nt2 * 16 + col;
            #pragma unroll
            for (int j = 0; j < 8; j++)
                dst[j] = f2b(w2[(c * 64 + kk2 * 32 + quad * 8 + j) * HH + n]);
        }
    } else {
        int bid = blockIdx.x - 256;
        __shared__ int stok[TT];
        if (bid < BB * PP) {
            if (tid < TT) stok[tid] = src[bid * TT + tid];
            __syncthreads();
            float acc = 0.f; int cnt = 0;
            #pragma unroll 8
            for (int i = 0; i < TT; i++) {
                int tk = stok[i];
                if (tk != 0) { cnt++; acc += emb[(size_t)tk * HH + tid]; }
            }
            g_para_feat[bid * HH + tid] = acc / fmaxf((float)cnt, 1.0f);
        } else {
            int cid = bid - BB * PP;
            if (tid < TCC) stok[tid] = cluster[cid * TCC + tid];
            __syncthreads();
            float acc = 0.f; int cnt = 0;
            #pragma unroll 8
            for (int i = 0; i < TCC; i++) {
                int tk = stok[i];
                if (tk != 0) { cnt++; acc += emb[(size_t)tk * HH + tid]; }
            }
            g_clus_feat[cid * HH + tid] = acc / fmaxf((float)cnt, 1.0f);
        }
    }
}

// ---------------------------------------------------------------------------
// GAT q/k/v projection into g_qb/g_kb/g_vb. grid (max(rq,rk), 3) x 256.
// ---------------------------------------------------------------------------
__global__ void k_proj(const float* __restrict__ qsrc, const float* __restrict__ kvsrc,
                       int rows_q, int rows_k,
                       const float* __restrict__ wq, const float* __restrict__ wk,
                       const float* __restrict__ wv) {
    int r = blockIdx.x, which = blockIdx.y, tid = threadIdx.x;
    const float* src; const float* w; float* dst; int rows;
    if (which == 0)      { src = qsrc;  w = wq; dst = g_qb; rows = rows_q; }
    else if (which == 1) { src = kvsrc; w = wk; dst = g_kb; rows = rows_k; }
    else                 { src = kvsrc; w = wv; dst = g_vb; rows = rows_k; }
    if (r >= rows) return;
    __shared__ float xs[HH];
    xs[tid] = src[r * HH + tid];
    __syncthreads();
    float acc = 0.f;
    #pragma unroll 16
    for (int i = 0; i < HH; i++) acc += xs[i] * w[i * HH + tid];
    dst[r * HH + tid] = acc;
}

// ---------------------------------------------------------------------------
// GAT attention + output projection + residual. One block per (b, q_node).
// ---------------------------------------------------------------------------
__global__ void k_attn(const float* __restrict__ qn, const int* __restrict__ edge,
                       const float* __restrict__ wo, float* __restrict__ dst,
                       float* __restrict__ out2, int Nq, int Nk, int p2c) {
    int r = blockIdx.x, tid = threadIdx.x;
    int b = r / Nq, qi = r % Nq;
    __shared__ float q_s[HH];
    __shared__ float o_s[HH];
    __shared__ float p_s[NHH][32];
    __shared__ float ssum[NHH];
    __shared__ int   msk[32];
    __shared__ int   hasnb;

    q_s[tid] = g_qb[r * HH + tid];
    if (tid < Nk) {
        int e = p2c ? edge[(b * PP + qi) * CC + tid]
                    : edge[(b * PP + tid) * CC + qi];
        msk[tid] = (e > 0) ? 1 : 0;
    }
    __syncthreads();

    int h = tid >> 5, kk = tid & 31;
    float sc = -1e9f;
    if (kk < Nk) {
        const float* krow = g_kb + (size_t)(b * Nk + kk) * HH + h * DD;
        float acc = 0.f;
        #pragma unroll
        for (int d2 = 0; d2 < DD; d2++) acc += q_s[h * DD + d2] * krow[d2];
        sc = msk[kk] ? acc * 0.17677669529663687f : -1e9f;  // 1/sqrt(32)
    }
    p_s[h][kk] = sc;
    __syncthreads();

    if (tid < NHH) {
        float mx = -1e30f;
        for (int k2 = 0; k2 < Nk; k2++) mx = fmaxf(mx, p_s[tid][k2]);
        float sm = 0.f;
        for (int k2 = 0; k2 < Nk; k2++) {
            float e2 = __expf(p_s[tid][k2] - mx);
            p_s[tid][k2] = e2; sm += e2;
        }
        ssum[tid] = sm;
    }
    if (tid == 0) {
        int a = 0;
        for (int k2 = 0; k2 < Nk; k2++) a |= msk[k2];
        hasnb = a;
    }
    __syncthreads();

    {
        float inv = 1.f / ssum[h];
        float o = 0.f;
        #pragma unroll
        for (int k2 = 0; k2 < 32; k2++) {
            if (k2 < Nk)
                o += p_s[h][k2] * g_vb[(size_t)(b * Nk + k2) * HH + h * DD + kk];
        }
        o_s[tid] = o * inv;
    }
    __syncthreads();

    float acc = 0.f;
    #pragma unroll 16
    for (int i = 0; i < HH; i++) acc += o_s[i] * wo[i * HH + tid];
    float res = qn[r * HH + tid] + (hasnb ? acc : 0.f);
    dst[r * HH + tid] = res;
    if (out2) out2[r * HH + tid] = res;
}

// ---------------------------------------------------------------------------
// Fused FFN, bf16 MFMA, LDS-staged weights. 64 tokens/block, grid 256.
// Per 64-col hidden chunk: stage W1c (32 KB) + W2c (32 KB) to LDS, GEMM1 ->
// relu -> wave-private C->A roundtrip -> GEMM2 partial. ~112 KB LDS.
// mfma_f32_16x16x32_bf16: A[m=lane&15][k=quad*8+j], B[k][n=lane&15],
// C/D[row=quad*4+reg][col=lane&15].
// ---------------------------------------------------------------------------
__global__ void __launch_bounds__(256) k_ffn_mfma(
        const int* __restrict__ src, const float* __restrict__ emb,
        const float* __restrict__ b1, const float* __restrict__ b2v,
        const float* __restrict__ lng, const float* __restrict__ lnb,
        float* __restrict__ out_ctx) {
    // xf (fp32 LN input) aliases the weight staging buffers (disjoint phases).
    __shared__ __align__(16) char uni[66560];       // xf[64][260] f32 | w1s+w2s
    __shared__ __align__(16) short xn[64][264];     // LN output bf16 (+8 pad)
    __shared__ __align__(16) short sbuf[4][16][72]; // per-wave hidden chunk
    __shared__ float red_s[64][4], red_s2[64][4];
    __shared__ float mu[64], rsd[64];
    __shared__ int   toks[64];

    float* xf  = (float*)uni;               // [m][d] at m*260+d
    short* w1s = (short*)uni;               // 16384 shorts
    short* w2s = (short*)(uni + 32768);     // 16384 shorts

    int tid = threadIdx.x;
    int t0 = blockIdx.x * 64;
    int pr = blockIdx.x >> 1;               // paragraph row (64 tokens = T/2)

    if (tid < 64) toks[tid] = src[t0 + tid];
    __syncthreads();

    {   // ph1: coalesced x = emb+ps -> xf (fp32)
        const float* psrow = g_para_state + pr * HH;
        float psv = psrow[tid];
        #pragma unroll 8
        for (int m = 0; m < 64; m++) {
            int tk = toks[m];
            float x = (tk ? emb[(size_t)tk * HH + tid] : 0.f) + psv;
            xf[m * 260 + tid] = x;
        }
    }
    __syncthreads();
    {   // ph2: LN stats from LDS, 4 threads per token
        int m = tid >> 2, q = tid & 3;
        float s = 0.f, s2 = 0.f;
        #pragma unroll
        for (int j = 0; j < 64; j++) {
            float v = xf[m * 260 + q * 64 + j];
            s += v; s2 += v * v;
        }
        red_s[m][q] = s; red_s2[m][q] = s2;
    }
    __syncthreads();
    if (tid < 64) {
        float s  = red_s [tid][0] + red_s [tid][1] + red_s [tid][2] + red_s [tid][3];
        float s2 = red_s2[tid][0] + red_s2[tid][1] + red_s2[tid][2] + red_s2[tid][3];
        float mean = s * (1.f / HH);
        float var  = s2 * (1.f / HH) - mean * mean;
        mu[tid] = mean; rsd[tid] = rsqrtf(var + 1e-6f);
    }
    __syncthreads();
    {   // ph4: normalize fp32 -> xn bf16
        float g = lng[tid], bt = lnb[tid];
        #pragma unroll 8
        for (int m = 0; m < 64; m++)
            xn[m][tid] = f2b((xf[m * 260 + tid] - mu[m]) * rsd[m] * g + bt);
    }
    __syncthreads();   // xf dead; staging may overwrite uni

    int wv = tid >> 6, lane = tid & 63, quad = lane >> 4, col = lane & 15;

    f32x4 acc2[16];
    #pragma unroll
    for (int i = 0; i < 16; i++) acc2[i] = (f32x4){0.f, 0.f, 0.f, 0.f};

    for (int c = 0; c < 16; c++) {
        // stage chunk weights: 64 KB, 16 independent b128 loads/thread
        #pragma unroll
        for (int it = 0; it < 8; it++) {
            int g = it * 256 + tid;                 // granule 0..2047
            *(bh8*)(w1s + g * 8) = *(const bh8*)(g_w1p + ((size_t)c * 2048 + g) * 8);
            *(bh8*)(w2s + g * 8) = *(const bh8*)(g_w2p + ((size_t)c * 2048 + g) * 8);
        }
        __syncthreads();

        f32x4 acc1[4];
        #pragma unroll
        for (int i = 0; i < 4; i++) acc1[i] = (f32x4){0.f, 0.f, 0.f, 0.f};

        #pragma unroll
        for (int kk = 0; kk < 8; kk++) {            // K1 = 256
            bh8 a = *(const bh8*)&xn[16 * wv + col][kk * 32 + quad * 8];
            #pragma unroll
            for (int nt = 0; nt < 4; nt++) {
                bh8 b = *(const bh8*)(w1s + ((kk * 4 + nt) * 64 + lane) * 8);
                acc1[nt] = __builtin_amdgcn_mfma_f32_16x16x32_bf16(a, b, acc1[nt], 0, 0, 0);
            }
        }
        // relu + bias -> wave-private LDS (A-layout for GEMM2); wave-local
        #pragma unroll
        for (int nt = 0; nt < 4; nt++) {
            float bias = b1[c * 64 + nt * 16 + col];
            #pragma unroll
            for (int r = 0; r < 4; r++) {
                float v = acc1[nt][r] + bias;
                sbuf[wv][quad * 4 + r][nt * 16 + col] = f2b(v > 0.f ? v : 0.f);
            }
        }
        #pragma unroll
        for (int kk2 = 0; kk2 < 2; kk2++) {         // chunk K2 = 64
            bh8 a2 = *(const bh8*)&sbuf[wv][col][kk2 * 32 + quad * 8];
            #pragma unroll
            for (int nt2 = 0; nt2 < 16; nt2++) {
                bh8 b = *(const bh8*)(w2s + ((kk2 * 16 + nt2) * 64 + lane) * 8);
                acc2[nt2] = __builtin_amdgcn_mfma_f32_16x16x32_bf16(a2, b, acc2[nt2], 0, 0, 0);
            }
        }
        __syncthreads();   // protect w1s/w2s until all waves done
    }

    // Epilogue: + b2 + residual (recomputed fp32-exact), mask, store
    #pragma unroll
    for (int nt2 = 0; nt2 < 16; nt2++) {
        int n = nt2 * 16 + col;
        float bias = b2v[n];
        #pragma unroll
        for (int r = 0; r < 4; r++) {
            int ml = 16 * wv + quad * 4 + r;
            int gt = t0 + ml;
            int tk = toks[ml];
            float x = (tk ? emb[(size_t)tk * HH + n] : 0.f) + g_para_state[pr * HH + n];
            float v = tk ? (acc2[nt2][r] + bias + x) : 0.f;
            out_ctx[(size_t)gt * HH + n] = v;
        }
    }
}

// ---------------------------------------------------------------------------
extern "C" void kernel_launch(void* const* d_in, const int* in_sizes, int n_in,
                              void* d_out, int out_size, void* d_ws, size_t ws_size,
                              hipStream_t stream) {
    const int*   src     = (const int*)d_in[0];
    const int*   cluster = (const int*)d_in[1];
    const int*   edge    = (const int*)d_in[2];
    const float* emb     = (const float*)d_in[3];
    const float* p2c_wq  = (const float*)d_in[4];
    const float* p2c_wk  = (const float*)d_in[5];
    const float* p2c_wv  = (const float*)d_in[6];
    const float* p2c_wo  = (const float*)d_in[7];
    const float* c2p_wq  = (const float*)d_in[8];
    const float* c2p_wk  = (const float*)d_in[9];
    const float* c2p_wv  = (const float*)d_in[10];
    const float* c2p_wo  = (const float*)d_in[11];
    const float* w1      = (const float*)d_in[12];
    const float* b1      = (const float*)d_in[13];
    const float* w2      = (const float*)d_in[14];
    const float* b2p     = (const float*)d_in[15];
    const float* lng     = (const float*)d_in[16];
    const float* lnb     = (const float*)d_in[17];
    // d_in[18..20]: gat_iter=2, padding_idx=0, n_heads=8 (hard-coded)

    float *para_feat, *clus_feat, *para_state, *clus_state;
    hipGetSymbolAddress((void**)&para_feat,  HIP_SYMBOL(g_para_feat));
    hipGetSymbolAddress((void**)&clus_feat,  HIP_SYMBOL(g_clus_feat));
    hipGetSymbolAddress((void**)&para_state, HIP_SYMBOL(g_para_state));
    hipGetSymbolAddress((void**)&clus_state, HIP_SYMBOL(g_clus_state));

    float* out      = (float*)d_out;
    float* out_ctx  = out + BB * PP * HH;                       // para_context
    float* out_clus = out + BB * PP * HH + BB * PP * TT * HH;   // cluster_state

    k_prep<<<dim3(448), dim3(256), 0, stream>>>(w1, w2, src, cluster, emb);

    auto gat = [&](const float* qsrc, const float* kvsrc, float* dst, float* out2,
                   const float* wq, const float* wk, const float* wv, const float* wo,
                   int Nq, int Nk, int p2c) {
        int rq = BB * Nq, rk = BB * Nk;
        int gx = rq > rk ? rq : rk;
        k_proj<<<dim3(gx, 3), dim3(256), 0, stream>>>(qsrc, kvsrc, rq, rk, wq, wk, wv);
        k_attn<<<dim3(rq), dim3(256), 0, stream>>>(qsrc, edge, wo, dst, out2, Nq, Nk, p2c);
    };

    gat(para_feat,  clus_feat,  para_state, nullptr,  p2c_wq, p2c_wk, p2c_wv, p2c_wo, PP, CC, 1);
    gat(clus_feat,  para_state, clus_state, nullptr,  c2p_wq, c2p_wk, c2p_wv, c2p_wo, CC, PP, 0);
    gat(para_state, clus_state, para_state, nullptr,  p2c_wq, p2c_wk, p2c_wv, p2c_wo, PP, CC, 1);
    gat(clus_state, para_state, clus_state, out_clus, c2p_wq, c2p_wk, c2p_wv, c2p_wo, CC, PP, 0);
    gat(para_state, clus_state, para_state, out,      p2c_wq, p2c_wk, p2c_wv, p2c_wo, PP, CC, 1);

    k_ffn_mfma<<<dim3(256), dim3(256), 0, stream>>>(src, emb, b1, b2p, lng, lnb, out_ctx);
}

// Round 7
// 335.652 us; speedup vs baseline: 2.3325x; 1.0098x over previous
//
#include <hip/hip_runtime.h>
#include <hip/hip_bf16.h>

// Problem constants (fixed by setup_inputs):
#define BB 4
#define PP 32
#define TT 128
#define CC 16
#define TCC 64
#define HH 256
#define NHH 8
#define DD 32      // HH / NHH
#define FFF 1024
// gat_iter=2, padding_idx=0, n_heads=8 hard-coded.
// Inputs fp32, output fp32 (established; rounds 4-6 passed).

typedef __attribute__((ext_vector_type(8))) short bh8;    // 8 bf16 (4 VGPRs)
typedef __attribute__((ext_vector_type(4))) float f32x4;  // MFMA C/D

// Device-global scratch (fully rewritten before read every launch).
__device__ float g_para_feat [BB * PP * HH];
__device__ float g_clus_feat [BB * CC * HH];
__device__ float g_para_state[BB * PP * HH];
// FFN weights, fragment-packed bf16, chunk-contiguous (16 chunks x 64 cols):
// g_w1p: [c][kk(8)][nt(4)][lane(64)][j(8)]
// g_w2p: [c][kk2(2)][nt2(16)][lane(64)][j(8)]
__device__ __align__(16) short g_w1p[HH * FFF];
__device__ __align__(16) short g_w2p[FFF * HH];
// GAT weights: 8 matrices (p2c wq,wk,wv,wo, c2p wq,wk,wv,wo), each
// [kk(8)][nt(16)][lane(64)][j(8)]  (B-frag: B[k=kk*32+quad*8+j][n=nt*16+col])
__device__ __align__(16) short g_gatw[8 * HH * HH];

__device__ __forceinline__ short f2b(float f) {
    union { __hip_bfloat16 h; short s; } u;
    u.h = __float2bfloat16(f);
    return u.s;
}
__device__ __forceinline__ float bs2f(short s) {
    union { float f; unsigned u; } x;
    x.u = ((unsigned)(unsigned short)s) << 16;
    return x.f;
}
__device__ __forceinline__ bh8 cvt8(f32x4 lo, f32x4 hi) {
    bh8 r;
    r[0] = f2b(lo[0]); r[1] = f2b(lo[1]); r[2] = f2b(lo[2]); r[3] = f2b(lo[3]);
    r[4] = f2b(hi[0]); r[5] = f2b(hi[1]); r[6] = f2b(hi[2]); r[7] = f2b(hi[3]);
    return r;
}

// ---------------------------------------------------------------------------
// k_prep: [0,256) pack W1/W2; [256,448) encode feats; [448,704) pack GAT Ws.
// ---------------------------------------------------------------------------
__global__ void __launch_bounds__(256) k_prep(
        const float* __restrict__ w1, const float* __restrict__ w2,
        const float* __restrict__ pq, const float* __restrict__ pk,
        const float* __restrict__ pv, const float* __restrict__ po,
        const float* __restrict__ cq, const float* __restrict__ ck,
        const float* __restrict__ cv, const float* __restrict__ co,
        const int* __restrict__ src, const int* __restrict__ cluster,
        const float* __restrict__ emb) {
    int tid = threadIdx.x;
    if (blockIdx.x < 256) {
        int idx = blockIdx.x * 256 + tid;
        int lane = idx & 63, quad = (lane >> 4) & 3, col = lane & 15;
        if (idx < 32768) {                   // W1 frags
            int f = idx >> 6;
            int nt = f & 3, kk = (f >> 2) & 7, c = f >> 5;
            short* dst = g_w1p + (size_t)idx * 8;
            int n = c * 64 + nt * 16 + col;
            #pragma unroll
            for (int j = 0; j < 8; j++)
                dst[j] = f2b(w1[(kk * 32 + quad * 8 + j) * FFF + n]);
        } else {                             // W2 frags
            int id2 = idx - 32768;
            int f = id2 >> 6;
            int nt2 = f & 15, kk2 = (f >> 4) & 1, c = f >> 5;
            short* dst = g_w2p + (size_t)id2 * 8;
            int n = nt2 * 16 + col;
            #pragma unroll
            for (int j = 0; j < 8; j++)
                dst[j] = f2b(w2[(c * 64 + kk2 * 32 + quad * 8 + j) * HH + n]);
        }
    } else if (blockIdx.x < 448) {
        int bid = blockIdx.x - 256;
        __shared__ int stok[TT];
        if (bid < BB * PP) {
            if (tid < TT) stok[tid] = src[bid * TT + tid];
            __syncthreads();
            float acc = 0.f; int cnt = 0;
            #pragma unroll 8
            for (int i = 0; i < TT; i++) {
                int tk = stok[i];
                if (tk != 0) { cnt++; acc += emb[(size_t)tk * HH + tid]; }
            }
            g_para_feat[bid * HH + tid] = acc / fmaxf((float)cnt, 1.0f);
        } else {
            int cid = bid - BB * PP;
            if (tid < TCC) stok[tid] = cluster[cid * TCC + tid];
            __syncthreads();
            float acc = 0.f; int cnt = 0;
            #pragma unroll 8
            for (int i = 0; i < TCC; i++) {
                int tk = stok[i];
                if (tk != 0) { cnt++; acc += emb[(size_t)tk * HH + tid]; }
            }
            g_clus_feat[cid * HH + tid] = acc / fmaxf((float)cnt, 1.0f);
        }
    } else {
        int pid = blockIdx.x - 448;          // 0..255
        int mat = pid >> 5;                  // 0..7
        int gi = (pid & 31) * 256 + tid;     // granule 0..8191
        int lane = gi & 63, quad = (lane >> 4) & 3, col = lane & 15;
        int f = gi >> 6;                     // 0..127
        int nt = f & 15, kk = f >> 4;
        const float* ws = (mat == 0) ? pq : (mat == 1) ? pk : (mat == 2) ? pv :
                          (mat == 3) ? po : (mat == 4) ? cq : (mat == 5) ? ck :
                          (mat == 6) ? cv : co;
        short* dst = g_gatw + ((size_t)mat * 8192 + gi) * 8;
        int n = nt * 16 + col;
        #pragma unroll
        for (int j = 0; j < 8; j++)
            dst[j] = f2b(ws[(kk * 32 + quad * 8 + j) * HH + n]);
    }
}

// ---------------------------------------------------------------------------
// Fused GAT layer (device helper). 512 threads = 8 waves, wave owns 32 N-cols.
// qb (Nq rows) updated in place: qb += hasnb * (attn(qb,kvb) @ wo).
// wm: base of 4 packed matrices (wq,wk,wv,wo). All frag layouts per §3.
// ---------------------------------------------------------------------------
template<int NQ, int NK, int P2C>
__device__ void gat_layer(int tid, float (*__restrict__ qb)[264],
                          float (*__restrict__ kvb)[264],
                          const short* __restrict__ wm, const int* __restrict__ eb,
                          float (*__restrict__ sq)[264], short (*__restrict__ sk)[264],
                          short (*__restrict__ sv)[264], short (*__restrict__ so)[264],
                          int* __restrict__ hasnb) {
    int w = tid >> 6, lane = tid & 63, quad = (lane >> 4) & 3, col = lane & 15;
    int nt0 = 2 * w;

    // ---- projections q (f32 out), k, v (bf16 out) ----
    #pragma unroll
    for (int mi = 0; mi < 3; mi++) {
        const float (*srcb)[264] = (mi == 0) ? qb : kvb;
        const int M = (mi == 0) ? NQ : NK;
        const int mtn = M >> 4;
        const short* bbase = wm + mi * 65536;
        f32x4 acc[2][2];
        #pragma unroll
        for (int a = 0; a < 2; a++)
            #pragma unroll
            for (int c2 = 0; c2 < 2; c2++) acc[a][c2] = (f32x4){0.f, 0.f, 0.f, 0.f};
        #pragma unroll
        for (int kk = 0; kk < 8; kk++) {
            bh8 b0 = *(const bh8*)(bbase + ((kk * 16 + nt0) * 64 + lane) * 8);
            bh8 b1 = *(const bh8*)(bbase + ((kk * 16 + nt0 + 1) * 64 + lane) * 8);
            #pragma unroll
            for (int mt = 0; mt < 2; mt++) {
                if (mt < mtn) {
                    f32x4 alo = *(const f32x4*)&srcb[mt * 16 + col][kk * 32 + quad * 8];
                    f32x4 ahi = *(const f32x4*)&srcb[mt * 16 + col][kk * 32 + quad * 8 + 4];
                    bh8 a = cvt8(alo, ahi);
                    acc[mt][0] = __builtin_amdgcn_mfma_f32_16x16x32_bf16(a, b0, acc[mt][0], 0, 0, 0);
                    acc[mt][1] = __builtin_amdgcn_mfma_f32_16x16x32_bf16(a, b1, acc[mt][1], 0, 0, 0);
                }
            }
        }
        #pragma unroll
        for (int mt = 0; mt < 2; mt++) {
            if (mt < mtn) {
                #pragma unroll
                for (int ntl = 0; ntl < 2; ntl++) {
                    #pragma unroll
                    for (int r = 0; r < 4; r++) {
                        int row = mt * 16 + quad * 4 + r;
                        int n = (nt0 + ntl) * 16 + col;
                        float v = acc[mt][ntl][r];
                        if (mi == 0)      sq[row][n] = v;
                        else if (mi == 1) sk[row][n] = f2b(v);
                        else              sv[row][n] = f2b(v);
                    }
                }
            }
        }
    }
    __syncthreads();

    // ---- scores + softmax (regs), per (qi, head) thread ----
    float av[NK];
    int qi = tid >> 3, h = tid & 7;
    bool act = tid < NQ * 8;
    if (act) {
        float qreg[32];
        #pragma unroll
        for (int s4 = 0; s4 < 8; s4++) {
            f32x4 t = *(const f32x4*)&sq[qi][h * 32 + s4 * 4];
            qreg[s4 * 4 + 0] = t[0]; qreg[s4 * 4 + 1] = t[1];
            qreg[s4 * 4 + 2] = t[2]; qreg[s4 * 4 + 3] = t[3];
        }
        float mx = -1e30f; int any = 0;
        #pragma unroll
        for (int kk = 0; kk < NK; kk++) {
            float d = 0.f;
            #pragma unroll
            for (int sg = 0; sg < 4; sg++) {
                bh8 kv = *(const bh8*)&sk[kk][h * 32 + sg * 8];
                #pragma unroll
                for (int e = 0; e < 8; e++) d += qreg[sg * 8 + e] * bs2f(kv[e]);
            }
            int eg = P2C ? eb[qi * CC + kk] : eb[kk * CC + qi];
            any |= (eg > 0);
            av[kk] = (eg > 0) ? d * 0.17677669529663687f : -1e9f;
            mx = fmaxf(mx, av[kk]);
        }
        float sm = 0.f;
        #pragma unroll
        for (int kk = 0; kk < NK; kk++) { av[kk] = __expf(av[kk] - mx); sm += av[kk]; }
        float inv = 1.f / sm;
        #pragma unroll
        for (int kk = 0; kk < NK; kk++) av[kk] *= inv;
        if (h == 0) hasnb[qi] = any;
    }
    __syncthreads();
    if (act) {
        #pragma unroll
        for (int kk = 0; kk < NK; kk++) sq[qi][h * 32 + kk] = av[kk];  // sq reused as P
    }
    __syncthreads();

    // ---- o = P @ v -> so (bf16). thread owns dim d = tid&255, qi = 2*rep+hi ----
    {
        int d = tid & 255, hi = tid >> 8;
        int hh = d >> 5;
        float vreg[NK];
        #pragma unroll
        for (int kk = 0; kk < NK; kk++) vreg[kk] = bs2f(sv[kk][d]);
        #pragma unroll
        for (int rep = 0; rep < 16; rep++) {
            int oqi = rep * 2 + hi;
            if (oqi < NQ) {
                float o = 0.f;
                #pragma unroll
                for (int kk = 0; kk < NK; kk++) o += sq[oqi][hh * 32 + kk] * vreg[kk];
                so[oqi][d] = f2b(o);
            }
        }
    }
    __syncthreads();

    // ---- out = o @ wo ; qb += hasnb * out ----
    {
        const int mtn = NQ >> 4;
        const short* bbase = wm + 3 * 65536;
        f32x4 acc[2][2];
        #pragma unroll
        for (int a = 0; a < 2; a++)
            #pragma unroll
            for (int c2 = 0; c2 < 2; c2++) acc[a][c2] = (f32x4){0.f, 0.f, 0.f, 0.f};
        #pragma unroll
        for (int kk = 0; kk < 8; kk++) {
            bh8 b0 = *(const bh8*)(bbase + ((kk * 16 + nt0) * 64 + lane) * 8);
            bh8 b1 = *(const bh8*)(bbase + ((kk * 16 + nt0 + 1) * 64 + lane) * 8);
            #pragma unroll
            for (int mt = 0; mt < 2; mt++) {
                if (mt < mtn) {
                    bh8 a = *(const bh8*)&so[mt * 16 + col][kk * 32 + quad * 8];
                    acc[mt][0] = __builtin_amdgcn_mfma_f32_16x16x32_bf16(a, b0, acc[mt][0], 0, 0, 0);
                    acc[mt][1] = __builtin_amdgcn_mfma_f32_16x16x32_bf16(a, b1, acc[mt][1], 0, 0, 0);
                }
            }
        }
        #pragma unroll
        for (int mt = 0; mt < 2; mt++) {
            if (mt < mtn) {
                #pragma unroll
                for (int ntl = 0; ntl < 2; ntl++) {
                    #pragma unroll
                    for (int r = 0; r < 4; r++) {
                        int row = mt * 16 + quad * 4 + r;
                        int n = (nt0 + ntl) * 16 + col;
                        float res = qb[row][n] + (hasnb[row] ? acc[mt][ntl][r] : 0.f);
                        qb[row][n] = res;
                    }
                }
            }
        }
    }
    __syncthreads();
}

// ---------------------------------------------------------------------------
// k_gat: whole 5-layer GAT chain, 1 block per batch, states live in LDS.
// ---------------------------------------------------------------------------
__global__ void __launch_bounds__(512) k_gat(const int* __restrict__ edge,
                                             float* __restrict__ out_ps,
                                             float* __restrict__ out_cs) {
    __shared__ __align__(16) float s_ps[PP][264];
    __shared__ __align__(16) float s_cs[CC][264];
    __shared__ __align__(16) float s_q [PP][264];   // reused as softmax P
    __shared__ __align__(16) short s_k [PP][264];
    __shared__ __align__(16) short s_v [PP][264];
    __shared__ __align__(16) short s_o [PP][264];
    __shared__ int s_hasnb[PP];

    int b = blockIdx.x, tid = threadIdx.x;
    #pragma unroll
    for (int rep = 0; rep < 16; rep++) {
        int idx = rep * 512 + tid;
        s_ps[idx >> 8][idx & 255] = g_para_feat[b * PP * HH + idx];
    }
    #pragma unroll
    for (int rep = 0; rep < 8; rep++) {
        int idx = rep * 512 + tid;
        s_cs[idx >> 8][idx & 255] = g_clus_feat[b * CC * HH + idx];
    }
    __syncthreads();

    const int* eb = edge + b * PP * CC;
    const short* wmp = g_gatw;                 // p2c set
    const short* wmc = g_gatw + 4 * 65536;     // c2p set

    gat_layer<PP, CC, 1>(tid, s_ps, s_cs, wmp, eb, s_q, s_k, s_v, s_o, s_hasnb);
    gat_layer<CC, PP, 0>(tid, s_cs, s_ps, wmc, eb, s_q, s_k, s_v, s_o, s_hasnb);
    gat_layer<PP, CC, 1>(tid, s_ps, s_cs, wmp, eb, s_q, s_k, s_v, s_o, s_hasnb);
    gat_layer<CC, PP, 0>(tid, s_cs, s_ps, wmc, eb, s_q, s_k, s_v, s_o, s_hasnb);
    gat_layer<PP, CC, 1>(tid, s_ps, s_cs, wmp, eb, s_q, s_k, s_v, s_o, s_hasnb);

    #pragma unroll
    for (int rep = 0; rep < 16; rep++) {
        int idx = rep * 512 + tid;
        float v = s_ps[idx >> 8][idx & 255];
        out_ps[b * PP * HH + idx] = v;
        g_para_state[b * PP * HH + idx] = v;
    }
    #pragma unroll
    for (int rep = 0; rep < 8; rep++) {
        int idx = rep * 512 + tid;
        out_cs[b * CC * HH + idx] = s_cs[idx >> 8][idx & 255];
    }
}

// ---------------------------------------------------------------------------
// FFN v3: 64 tokens/block, grid 256. A-frags in registers, B-frags straight
// from L2. Waves split by N. LDS only for xn + chunk hidden (sbuf).
// ---------------------------------------------------------------------------
__global__ void __launch_bounds__(256, 1) k_ffn_mfma(
        const int* __restrict__ src, const float* __restrict__ emb,
        const float* __restrict__ b1, const float* __restrict__ b2v,
        const float* __restrict__ lng, const float* __restrict__ lnb,
        float* __restrict__ out_ctx) {
    __shared__ __align__(16) short xn[64][264];
    __shared__ __align__(16) short sbuf[64][72];
    __shared__ float red_s[64][4], red_s2[64][4];
    __shared__ float mu[64], rsd[64];
    __shared__ int   toks[64];

    int tid = threadIdx.x;
    int t0 = blockIdx.x * 64;
    int pr = blockIdx.x >> 1;
    const float* psr = g_para_state + pr * HH;

    if (tid < 64) toks[tid] = src[t0 + tid];
    __syncthreads();

    {   // LN stats: thread (m, quarter q) over global reads
        int m = tid >> 2, q = tid & 3;
        int tk = toks[m];
        const float* er = emb + (size_t)tk * HH;
        float s = 0.f, s2 = 0.f;
        #pragma unroll 8
        for (int j = 0; j < 64; j++) {
            int d = q * 64 + j;
            float x = (tk ? er[d] : 0.f) + psr[d];
            s += x; s2 += x * x;
        }
        red_s[m][q] = s; red_s2[m][q] = s2;
    }
    __syncthreads();
    if (tid < 64) {
        float s  = red_s [tid][0] + red_s [tid][1] + red_s [tid][2] + red_s [tid][3];
        float s2 = red_s2[tid][0] + red_s2[tid][1] + red_s2[tid][2] + red_s2[tid][3];
        float mean = s * (1.f / HH);
        float var  = s2 * (1.f / HH) - mean * mean;
        mu[tid] = mean; rsd[tid] = rsqrtf(var + 1e-6f);
    }
    __syncthreads();
    {   // normalize -> xn bf16 (coalesced: thread owns dim tid)
        float g = lng[tid], bt = lnb[tid];
        float psv = psr[tid];
        #pragma unroll 8
        for (int m = 0; m < 64; m++) {
            int tk = toks[m];
            float x = (tk ? emb[(size_t)tk * HH + tid] : 0.f) + psv;
            xn[m][tid] = f2b((x - mu[m]) * rsd[m] * g + bt);
        }
    }
    __syncthreads();

    int wv = tid >> 6, lane = tid & 63, quad = (lane >> 4) & 3, col = lane & 15;

    // A1 preload: 32 frags = 128 VGPRs (reused across all 16 chunks)
    bh8 A1[4][8];
    #pragma unroll
    for (int s = 0; s < 4; s++)
        #pragma unroll
        for (int kk = 0; kk < 8; kk++)
            A1[s][kk] = *(const bh8*)&xn[s * 16 + col][kk * 32 + quad * 8];

    f32x4 acc2[4][4];
    #pragma unroll
    for (int s = 0; s < 4; s++)
        #pragma unroll
        for (int j2 = 0; j2 < 4; j2++) acc2[s][j2] = (f32x4){0.f, 0.f, 0.f, 0.f};

    for (int c = 0; c < 16; c++) {
        float bias1 = b1[c * 64 + wv * 16 + col];
        // GEMM1: B straight from L2 (8 independent loads), 32 MFMAs
        bh8 B1[8];
        #pragma unroll
        for (int kk = 0; kk < 8; kk++)
            B1[kk] = *(const bh8*)(g_w1p + (((size_t)(c * 8 + kk) * 4 + wv) * 64 + lane) * 8);
        f32x4 acc1[4];
        #pragma unroll
        for (int s = 0; s < 4; s++) acc1[s] = (f32x4){0.f, 0.f, 0.f, 0.f};
        #pragma unroll
        for (int kk = 0; kk < 8; kk++)
            #pragma unroll
            for (int s = 0; s < 4; s++)
                acc1[s] = __builtin_amdgcn_mfma_f32_16x16x32_bf16(A1[s][kk], B1[kk], acc1[s], 0, 0, 0);
        // bias + relu -> sbuf (C-layout -> A-layout roundtrip)
        #pragma unroll
        for (int s = 0; s < 4; s++)
            #pragma unroll
            for (int r = 0; r < 4; r++) {
                float v = acc1[s][r] + bias1;
                sbuf[s * 16 + quad * 4 + r][wv * 16 + col] = f2b(v > 0.f ? v : 0.f);
            }
        __syncthreads();
        // GEMM2: wave owns out cols [wv*64, wv*64+64)
        #pragma unroll
        for (int kk2 = 0; kk2 < 2; kk2++) {
            bh8 B2[4];
            #pragma unroll
            for (int j2 = 0; j2 < 4; j2++)
                B2[j2] = *(const bh8*)(g_w2p + (((size_t)(c * 2 + kk2) * 16 + wv * 4 + j2) * 64 + lane) * 8);
            bh8 A2[4];
            #pragma unroll
            for (int s = 0; s < 4; s++)
                A2[s] = *(const bh8*)&sbuf[s * 16 + col][kk2 * 32 + quad * 8];
            #pragma unroll
            for (int j2 = 0; j2 < 4; j2++)
                #pragma unroll
                for (int s = 0; s < 4; s++)
                    acc2[s][j2] = __builtin_amdgcn_mfma_f32_16x16x32_bf16(A2[s], B2[j2], acc2[s][j2], 0, 0, 0);
        }
        __syncthreads();
    }

    // Epilogue: + b2 + residual (fp32-exact), mask, store
    #pragma unroll
    for (int j2 = 0; j2 < 4; j2++) {
        int n = (wv * 4 + j2) * 16 + col;
        float bias = b2v[n];
        float psv = psr[n];
        #pragma unroll
        for (int s = 0; s < 4; s++)
            #pragma unroll
            for (int r = 0; r < 4; r++) {
                int ml = s * 16 + quad * 4 + r;
                int gt = t0 + ml;
                int tk = toks[ml];
                float x = (tk ? emb[(size_t)tk * HH + n] : 0.f) + psv;
                out_ctx[(size_t)gt * HH + n] = tk ? (acc2[s][j2][r] + bias + x) : 0.f;
            }
    }
}

// ---------------------------------------------------------------------------
extern "C" void kernel_launch(void* const* d_in, const int* in_sizes, int n_in,
                              void* d_out, int out_size, void* d_ws, size_t ws_size,
                              hipStream_t stream) {
    const int*   src     = (const int*)d_in[0];
    const int*   cluster = (const int*)d_in[1];
    const int*   edge    = (const int*)d_in[2];
    const float* emb     = (const float*)d_in[3];
    const float* p2c_wq  = (const float*)d_in[4];
    const float* p2c_wk  = (const float*)d_in[5];
    const float* p2c_wv  = (const float*)d_in[6];
    const float* p2c_wo  = (const float*)d_in[7];
    const float* c2p_wq  = (const float*)d_in[8];
    const float* c2p_wk  = (const float*)d_in[9];
    const float* c2p_wv  = (const float*)d_in[10];
    const float* c2p_wo  = (const float*)d_in[11];
    const float* w1      = (const float*)d_in[12];
    const float* b1      = (const float*)d_in[13];
    const float* w2      = (const float*)d_in[14];
    const float* b2p     = (const float*)d_in[15];
    const float* lng     = (const float*)d_in[16];
    const float* lnb     = (const float*)d_in[17];
    // d_in[18..20]: gat_iter=2, padding_idx=0, n_heads=8 (hard-coded)

    float* out      = (float*)d_out;
    float* out_ctx  = out + BB * PP * HH;                       // para_context
    float* out_clus = out + BB * PP * HH + BB * PP * TT * HH;   // cluster_state

    k_prep<<<dim3(704), dim3(256), 0, stream>>>(w1, w2,
        p2c_wq, p2c_wk, p2c_wv, p2c_wo, c2p_wq, c2p_wk, c2p_wv, c2p_wo,
        src, cluster, emb);
    k_gat<<<dim3(BB), dim3(512), 0, stream>>>(edge, out, out_clus);
    k_ffn_mfma<<<dim3(256), dim3(256), 0, stream>>>(src, emb, b1, b2p, lng, lnb, out_ctx);
}

// Round 8
// 283.677 us; speedup vs baseline: 2.7598x; 1.1832x over previous
//
#include <hip/hip_runtime.h>
#include <hip/hip_bf16.h>

// Problem constants (fixed by setup_inputs):
#define BB 4
#define PP 32
#define TT 128
#define CC 16
#define TCC 64
#define HH 256
#define NHH 8
#define DD 32      // HH / NHH
#define FFF 1024
// gat_iter=2, padding_idx=0, n_heads=8 hard-coded.
// Inputs fp32, output fp32 (established; rounds 4-7 passed).

typedef __attribute__((ext_vector_type(8))) short bh8;    // 8 bf16 (4 VGPRs)
typedef __attribute__((ext_vector_type(4))) float f32x4;  // MFMA C/D

// Device-global scratch (fully rewritten before read every launch).
__device__ float g_para_feat [BB * PP * HH];
__device__ float g_clus_feat [BB * CC * HH];
__device__ float g_para_state[BB * PP * HH];
// FFN weights, fragment-packed bf16, chunk-contiguous (16 chunks x 64 cols):
// g_w1p: [c][kk(8)][nt(4)][lane(64)][j(8)]
// g_w2p: [c][kk2(2)][nt2(16)][lane(64)][j(8)]
__device__ __align__(16) short g_w1p[HH * FFF];
__device__ __align__(16) short g_w2p[FFF * HH];
// GAT weights: 8 matrices (p2c wq,wk,wv,wo, c2p wq,wk,wv,wo), each
// [kk(8)][nt(16)][lane(64)][j(8)]  (B-frag: B[k=kk*32+quad*8+j][n=nt*16+col])
__device__ __align__(16) short g_gatw[8 * HH * HH];

__device__ __forceinline__ short f2b(float f) {
    union { __hip_bfloat16 h; short s; } u;
    u.h = __float2bfloat16(f);
    return u.s;
}
__device__ __forceinline__ float bs2f(short s) {
    union { float f; unsigned u; } x;
    x.u = ((unsigned)(unsigned short)s) << 16;
    return x.f;
}

// ---------------------------------------------------------------------------
// k_prep: [0,256) pack W1/W2; [256,448) encode feats; [448,704) pack GAT Ws.
// ---------------------------------------------------------------------------
__global__ void __launch_bounds__(256) k_prep(
        const float* __restrict__ w1, const float* __restrict__ w2,
        const float* __restrict__ pq, const float* __restrict__ pk,
        const float* __restrict__ pv, const float* __restrict__ po,
        const float* __restrict__ cq, const float* __restrict__ ck,
        const float* __restrict__ cv, const float* __restrict__ co,
        const int* __restrict__ src, const int* __restrict__ cluster,
        const float* __restrict__ emb) {
    int tid = threadIdx.x;
    if (blockIdx.x < 256) {
        int idx = blockIdx.x * 256 + tid;
        int lane = idx & 63, quad = (lane >> 4) & 3, col = lane & 15;
        if (idx < 32768) {                   // W1 frags
            int f = idx >> 6;
            int nt = f & 3, kk = (f >> 2) & 7, c = f >> 5;
            short* dst = g_w1p + (size_t)idx * 8;
            int n = c * 64 + nt * 16 + col;
            #pragma unroll
            for (int j = 0; j < 8; j++)
                dst[j] = f2b(w1[(kk * 32 + quad * 8 + j) * FFF + n]);
        } else {                             // W2 frags
            int id2 = idx - 32768;
            int f = id2 >> 6;
            int nt2 = f & 15, kk2 = (f >> 4) & 1, c = f >> 5;
            short* dst = g_w2p + (size_t)id2 * 8;
            int n = nt2 * 16 + col;
            #pragma unroll
            for (int j = 0; j < 8; j++)
                dst[j] = f2b(w2[(c * 64 + kk2 * 32 + quad * 8 + j) * HH + n]);
        }
    } else if (blockIdx.x < 448) {
        int bid = blockIdx.x - 256;
        __shared__ int stok[TT];
        if (bid < BB * PP) {
            if (tid < TT) stok[tid] = src[bid * TT + tid];
            __syncthreads();
            float acc = 0.f; int cnt = 0;
            #pragma unroll 8
            for (int i = 0; i < TT; i++) {
                int tk = stok[i];
                if (tk != 0) { cnt++; acc += emb[(size_t)tk * HH + tid]; }
            }
            g_para_feat[bid * HH + tid] = acc / fmaxf((float)cnt, 1.0f);
        } else {
            int cid = bid - BB * PP;
            if (tid < TCC) stok[tid] = cluster[cid * TCC + tid];
            __syncthreads();
            float acc = 0.f; int cnt = 0;
            #pragma unroll 8
            for (int i = 0; i < TCC; i++) {
                int tk = stok[i];
                if (tk != 0) { cnt++; acc += emb[(size_t)tk * HH + tid]; }
            }
            g_clus_feat[cid * HH + tid] = acc / fmaxf((float)cnt, 1.0f);
        }
    } else {
        int pid = blockIdx.x - 448;          // 0..255
        int mat = pid >> 5;                  // 0..7
        int gi = (pid & 31) * 256 + tid;     // granule 0..8191
        int lane = gi & 63, quad = (lane >> 4) & 3, col = lane & 15;
        int f = gi >> 6;                     // 0..127
        int nt = f & 15, kk = f >> 4;
        const float* ws = (mat == 0) ? pq : (mat == 1) ? pk : (mat == 2) ? pv :
                          (mat == 3) ? po : (mat == 4) ? cq : (mat == 5) ? ck :
                          (mat == 6) ? cv : co;
        short* dst = g_gatw + ((size_t)mat * 8192 + gi) * 8;
        int n = nt * 16 + col;
        #pragma unroll
        for (int j = 0; j < 8; j++)
            dst[j] = f2b(ws[(kk * 32 + quad * 8 + j) * HH + n]);
    }
}

// ---------------------------------------------------------------------------
// GAT layer, all-MFMA. 512 threads = 8 waves share a balanced job list.
// States: qs fp32 + qsb bf16 mirror (A-layout rows [*][264]).
// mfma_f32_16x16x32_bf16: A[m=lane&15][k=quad*8+j], B[k][n=lane&15],
// C/D[row=quad*4+reg][col=lane&15].
// ---------------------------------------------------------------------------
template<int NQ, int NK>
__device__ void gat_layer(int tid,
                          float (*__restrict__ qs)[264], short (*__restrict__ qsb)[264],
                          short (*__restrict__ kvb)[264],
                          const short* __restrict__ wm,
                          const int* __restrict__ msk, const int* __restrict__ has,
                          short (*__restrict__ s_q)[264],   // also reused as O
                          short (*__restrict__ s_k)[264],
                          short (*__restrict__ s_vT)[44],
                          short (*__restrict__ s_pb)[32][44]) {
    const int MTQ = NQ / 16, MTK = NK / 16;
    int w = tid >> 6, lane = tid & 63, quad = (lane >> 4) & 3, col = lane & 15;

    // ---- Phase 1: q/k/v projections ----
    const int NJ1 = (MTQ + 2 * MTK) * 16;
    for (int jid = w; jid < NJ1; jid += 8) {
        int nt = jid & 15, t = jid >> 4;
        int mi, mt;
        if (t < MTQ)            { mi = 0; mt = t; }
        else if (t < MTQ + MTK) { mi = 1; mt = t - MTQ; }
        else                    { mi = 2; mt = t - MTQ - MTK; }
        const short (*Ab)[264] = (mi == 0) ? qsb : kvb;
        const short* bb = wm + mi * 65536;
        f32x4 acc = (f32x4){0.f, 0.f, 0.f, 0.f};
        #pragma unroll
        for (int kk = 0; kk < 8; kk++) {
            bh8 a = *(const bh8*)&Ab[mt * 16 + col][kk * 32 + quad * 8];
            bh8 bf = *(const bh8*)(bb + ((kk * 16 + nt) * 64 + lane) * 8);
            acc = __builtin_amdgcn_mfma_f32_16x16x32_bf16(a, bf, acc, 0, 0, 0);
        }
        #pragma unroll
        for (int r = 0; r < 4; r++) {
            int row = mt * 16 + quad * 4 + r, n = nt * 16 + col;
            if (mi == 0)      s_q[row][n] = f2b(acc[r]);
            else if (mi == 1) s_k[row][n] = f2b(acc[r]);
            else              s_vT[n][row] = f2b(acc[r]);     // transposed
        }
    }
    if (NK == 16) {     // zero vT pad rows [16,32) so P@V pad contributes 0
        int d = tid >> 1, o = 16 + (tid & 1) * 8;
        #pragma unroll
        for (int j = 0; j < 8; j++) s_vT[d][o + j] = 0;
    }
    __syncthreads();

    // ---- Phase 2: scores = Q_h @ K_h^T (per head), mask, scale ----
    for (int jid = w; jid < 8 * MTQ * MTK; jid += 8) {
        int h = jid & 7, rest = jid >> 3;
        int mt = rest % MTQ, nt = rest / MTQ;
        bh8 a  = *(const bh8*)&s_q[mt * 16 + col][h * 32 + quad * 8];
        bh8 bf = *(const bh8*)&s_k[nt * 16 + col][h * 32 + quad * 8];
        f32x4 acc = (f32x4){0.f, 0.f, 0.f, 0.f};
        acc = __builtin_amdgcn_mfma_f32_16x16x32_bf16(a, bf, acc, 0, 0, 0);
        #pragma unroll
        for (int r = 0; r < 4; r++) {
            int qrow = mt * 16 + quad * 4 + r, krow = nt * 16 + col;
            int bit = (msk[qrow] >> krow) & 1;
            s_pb[h][qrow][krow] = f2b(bit ? acc[r] * 0.17677669529663687f : -1e9f);
        }
    }
    __syncthreads();

    // ---- Phase 3: softmax per (qi, h), write normalized P (bf16, pad->0) ----
    if (tid < NQ * 8) {
        int qi = tid >> 3, h = tid & 7;
        float av[NK]; float mx = -1e30f;
        #pragma unroll
        for (int k = 0; k < NK; k++) { av[k] = bs2f(s_pb[h][qi][k]); mx = fmaxf(mx, av[k]); }
        float sm = 0.f;
        #pragma unroll
        for (int k = 0; k < NK; k++) { av[k] = __expf(av[k] - mx); sm += av[k]; }
        float inv = 1.f / sm;
        #pragma unroll
        for (int k = 0; k < NK; k++) s_pb[h][qi][k] = f2b(av[k] * inv);
        if (NK == 16) {
            #pragma unroll
            for (int k = 16; k < 32; k++) s_pb[h][qi][k] = 0;
        }
    }
    __syncthreads();

    // ---- Phase 4: O_h = P_h @ V_h  -> s_q reused as O ----
    for (int jid = w; jid < 8 * MTQ * 2; jid += 8) {
        int h = jid & 7, rest = jid >> 3;
        int mt = rest % MTQ, nt2 = rest / MTQ;
        bh8 a  = *(const bh8*)&s_pb[h][mt * 16 + col][quad * 8];
        bh8 bf = *(const bh8*)&s_vT[h * 32 + nt2 * 16 + col][quad * 8];
        f32x4 acc = (f32x4){0.f, 0.f, 0.f, 0.f};
        acc = __builtin_amdgcn_mfma_f32_16x16x32_bf16(a, bf, acc, 0, 0, 0);
        #pragma unroll
        for (int r = 0; r < 4; r++)
            s_q[mt * 16 + quad * 4 + r][h * 32 + nt2 * 16 + col] = f2b(acc[r]);
    }
    __syncthreads();

    // ---- Phase 5: out = O @ wo ; qs += hasnb * out ; refresh bf16 mirror ----
    for (int jid = w; jid < MTQ * 16; jid += 8) {
        int nt = jid & 15, mt = jid >> 4;
        const short* bb = wm + 3 * 65536;
        f32x4 acc = (f32x4){0.f, 0.f, 0.f, 0.f};
        #pragma unroll
        for (int kk = 0; kk < 8; kk++) {
            bh8 a = *(const bh8*)&s_q[mt * 16 + col][kk * 32 + quad * 8];
            bh8 bf = *(const bh8*)(bb + ((kk * 16 + nt) * 64 + lane) * 8);
            acc = __builtin_amdgcn_mfma_f32_16x16x32_bf16(a, bf, acc, 0, 0, 0);
        }
        #pragma unroll
        for (int r = 0; r < 4; r++) {
            int row = mt * 16 + quad * 4 + r, n = nt * 16 + col;
            float nv = qs[row][n] + (has[row] ? acc[r] : 0.f);
            qs[row][n] = nv;
            qsb[row][n] = f2b(nv);
        }
    }
    __syncthreads();
}

// ---------------------------------------------------------------------------
// k_gat: whole 5-layer chain, 1 block/batch, 512 threads, states in LDS.
// ---------------------------------------------------------------------------
__global__ void __launch_bounds__(512) k_gat(const int* __restrict__ edge,
                                             float* __restrict__ out_ps,
                                             float* __restrict__ out_cs) {
    __shared__ __align__(16) float s_ps [PP][264];
    __shared__ __align__(16) float s_cs [CC][264];
    __shared__ __align__(16) short s_psb[PP][264];
    __shared__ __align__(16) short s_csb[CC][264];
    __shared__ __align__(16) short s_q  [PP][264];
    __shared__ __align__(16) short s_k  [PP][264];
    __shared__ __align__(16) short s_vT [HH][44];
    __shared__ __align__(16) short s_pb [NHH][32][44];
    __shared__ int s_mskP[PP], s_hasP[PP], s_mskC[CC], s_hasC[CC];

    int b = blockIdx.x, tid = threadIdx.x;
    const int* eb = edge + b * PP * CC;

    #pragma unroll
    for (int rep = 0; rep < 16; rep++) {
        int idx = rep * 512 + tid;
        float v = g_para_feat[b * PP * HH + idx];
        s_ps[idx >> 8][idx & 255] = v;
        s_psb[idx >> 8][idx & 255] = f2b(v);
    }
    #pragma unroll
    for (int rep = 0; rep < 8; rep++) {
        int idx = rep * 512 + tid;
        float v = g_clus_feat[b * CC * HH + idx];
        s_cs[idx >> 8][idx & 255] = v;
        s_csb[idx >> 8][idx & 255] = f2b(v);
    }
    if (tid < PP) {
        int m = 0;
        #pragma unroll
        for (int k = 0; k < CC; k++) m |= (eb[tid * CC + k] > 0) << k;
        s_mskP[tid] = m; s_hasP[tid] = (m != 0);
    } else if (tid < PP + CC) {
        int ci = tid - PP, m = 0;
        #pragma unroll
        for (int p = 0; p < PP; p++) m |= (eb[p * CC + ci] > 0) << p;
        s_mskC[ci] = m; s_hasC[ci] = (m != 0);
    }
    __syncthreads();

    const short* wmp = g_gatw;                 // p2c set
    const short* wmc = g_gatw + 4 * 65536;     // c2p set

    gat_layer<PP, CC>(tid, s_ps, s_psb, s_csb, wmp, s_mskP, s_hasP, s_q, s_k, s_vT, s_pb);
    gat_layer<CC, PP>(tid, s_cs, s_csb, s_psb, wmc, s_mskC, s_hasC, s_q, s_k, s_vT, s_pb);
    gat_layer<PP, CC>(tid, s_ps, s_psb, s_csb, wmp, s_mskP, s_hasP, s_q, s_k, s_vT, s_pb);
    gat_layer<CC, PP>(tid, s_cs, s_csb, s_psb, wmc, s_mskC, s_hasC, s_q, s_k, s_vT, s_pb);
    gat_layer<PP, CC>(tid, s_ps, s_psb, s_csb, wmp, s_mskP, s_hasP, s_q, s_k, s_vT, s_pb);

    #pragma unroll
    for (int rep = 0; rep < 16; rep++) {
        int idx = rep * 512 + tid;
        float v = s_ps[idx >> 8][idx & 255];
        out_ps[b * PP * HH + idx] = v;
        g_para_state[b * PP * HH + idx] = v;
    }
    #pragma unroll
    for (int rep = 0; rep < 8; rep++) {
        int idx = rep * 512 + tid;
        out_cs[b * CC * HH + idx] = s_cs[idx >> 8][idx & 255];
    }
}

// ---------------------------------------------------------------------------
// FFN v4: 64 tokens/block, grid 256, 4 waves. Wave = (strip-pair sh, col-half
// ch). A-frags from LDS; B-frags from L2 in one independent batch per GEMM.
// ---------------------------------------------------------------------------
__global__ void __launch_bounds__(256, 1) k_ffn_mfma(
        const int* __restrict__ src, const float* __restrict__ emb,
        const float* __restrict__ b1, const float* __restrict__ b2v,
        const float* __restrict__ lng, const float* __restrict__ lnb,
        float* __restrict__ out_ctx) {
    __shared__ __align__(16) short xn[64][264];
    __shared__ __align__(16) short sbuf[64][72];
    __shared__ float red_s[64][4], red_s2[64][4];
    __shared__ float mu[64], rsd[64];
    __shared__ int   toks[64];

    int tid = threadIdx.x;
    int t0 = blockIdx.x * 64;
    int pr = blockIdx.x >> 1;
    const float* psr = g_para_state + pr * HH;

    if (tid < 64) toks[tid] = src[t0 + tid];
    __syncthreads();

    {   // LN stats
        int m = tid >> 2, q = tid & 3;
        int tk = toks[m];
        const float* er = emb + (size_t)tk * HH;
        float s = 0.f, s2 = 0.f;
        #pragma unroll 8
        for (int j = 0; j < 64; j++) {
            int d = q * 64 + j;
            float x = (tk ? er[d] : 0.f) + psr[d];
            s += x; s2 += x * x;
        }
        red_s[m][q] = s; red_s2[m][q] = s2;
    }
    __syncthreads();
    if (tid < 64) {
        float s  = red_s [tid][0] + red_s [tid][1] + red_s [tid][2] + red_s [tid][3];
        float s2 = red_s2[tid][0] + red_s2[tid][1] + red_s2[tid][2] + red_s2[tid][3];
        float mean = s * (1.f / HH);
        float var  = s2 * (1.f / HH) - mean * mean;
        mu[tid] = mean; rsd[tid] = rsqrtf(var + 1e-6f);
    }
    __syncthreads();
    {   // normalize -> xn bf16
        float g = lng[tid], bt = lnb[tid];
        float psv = psr[tid];
        #pragma unroll 8
        for (int m = 0; m < 64; m++) {
            int tk = toks[m];
            float x = (tk ? emb[(size_t)tk * HH + tid] : 0.f) + psv;
            xn[m][tid] = f2b((x - mu[m]) * rsd[m] * g + bt);
        }
    }
    __syncthreads();

    int wv = tid >> 6, lane = tid & 63, quad = (lane >> 4) & 3, col = lane & 15;
    int sh = wv & 1, ch = wv >> 1;

    f32x4 acc2[2][8];
    #pragma unroll
    for (int si = 0; si < 2; si++)
        #pragma unroll
        for (int j2 = 0; j2 < 8; j2++) acc2[si][j2] = (f32x4){0.f, 0.f, 0.f, 0.f};

    for (int c = 0; c < 16; c++) {
        // GEMM1: B1 = 16 frags from L2 (independent batch)
        bh8 B1[8][2];
        #pragma unroll
        for (int kk = 0; kk < 8; kk++)
            #pragma unroll
            for (int nt = 0; nt < 2; nt++)
                B1[kk][nt] = *(const bh8*)(g_w1p +
                    (((size_t)(c * 8 + kk) * 4 + ch * 2 + nt) * 64 + lane) * 8);
        f32x4 acc1[2][2];
        #pragma unroll
        for (int si = 0; si < 2; si++)
            #pragma unroll
            for (int nt = 0; nt < 2; nt++) acc1[si][nt] = (f32x4){0.f, 0.f, 0.f, 0.f};
        #pragma unroll
        for (int kk = 0; kk < 8; kk++) {
            #pragma unroll
            for (int si = 0; si < 2; si++) {
                bh8 a = *(const bh8*)&xn[(sh * 2 + si) * 16 + col][kk * 32 + quad * 8];
                acc1[si][0] = __builtin_amdgcn_mfma_f32_16x16x32_bf16(a, B1[kk][0], acc1[si][0], 0, 0, 0);
                acc1[si][1] = __builtin_amdgcn_mfma_f32_16x16x32_bf16(a, B1[kk][1], acc1[si][1], 0, 0, 0);
            }
        }
        // B2 for this chunk: issue early (latency hidden by epilogue+barrier)
        bh8 B2[2][8];
        #pragma unroll
        for (int kk2 = 0; kk2 < 2; kk2++)
            #pragma unroll
            for (int j2 = 0; j2 < 8; j2++)
                B2[kk2][j2] = *(const bh8*)(g_w2p +
                    (((size_t)(c * 2 + kk2) * 16 + ch * 8 + j2) * 64 + lane) * 8);
        // bias + relu -> sbuf
        #pragma unroll
        for (int si = 0; si < 2; si++)
            #pragma unroll
            for (int nt = 0; nt < 2; nt++) {
                float bias = b1[c * 64 + ch * 32 + nt * 16 + col];
                #pragma unroll
                for (int r = 0; r < 4; r++) {
                    float v = acc1[si][nt][r] + bias;
                    sbuf[(sh * 2 + si) * 16 + quad * 4 + r][ch * 32 + nt * 16 + col] =
                        f2b(v > 0.f ? v : 0.f);
                }
            }
        __syncthreads();
        // GEMM2 over this chunk's 64 K-dims
        #pragma unroll
        for (int kk2 = 0; kk2 < 2; kk2++) {
            #pragma unroll
            for (int si = 0; si < 2; si++) {
                bh8 a2 = *(const bh8*)&sbuf[(sh * 2 + si) * 16 + col][kk2 * 32 + quad * 8];
                #pragma unroll
                for (int j2 = 0; j2 < 8; j2++)
                    acc2[si][j2] = __builtin_amdgcn_mfma_f32_16x16x32_bf16(a2, B2[kk2][j2], acc2[si][j2], 0, 0, 0);
            }
        }
        __syncthreads();
    }

    // Epilogue: + b2 + residual (fp32-exact), mask, store
    #pragma unroll
    for (int j2 = 0; j2 < 8; j2++) {
        int n = ch * 128 + j2 * 16 + col;
        float bias = b2v[n];
        float psv = psr[n];
        #pragma unroll
        for (int si = 0; si < 2; si++)
            #pragma unroll
            for (int r = 0; r < 4; r++) {
                int ml = (sh * 2 + si) * 16 + quad * 4 + r;
                int gt = t0 + ml;
                int tk = toks[ml];
                float x = (tk ? emb[(size_t)tk * HH + n] : 0.f) + psv;
                out_ctx[(size_t)gt * HH + n] = tk ? (acc2[si][j2][r] + bias + x) : 0.f;
            }
    }
}

// ---------------------------------------------------------------------------
extern "C" void kernel_launch(void* const* d_in, const int* in_sizes, int n_in,
                              void* d_out, int out_size, void* d_ws, size_t ws_size,
                              hipStream_t stream) {
    const int*   src     = (const int*)d_in[0];
    const int*   cluster = (const int*)d_in[1];
    const int*   edge    = (const int*)d_in[2];
    const float* emb     = (const float*)d_in[3];
    const float* p2c_wq  = (const float*)d_in[4];
    const float* p2c_wk  = (const float*)d_in[5];
    const float* p2c_wv  = (const float*)d_in[6];
    const float* p2c_wo  = (const float*)d_in[7];
    const float* c2p_wq  = (const float*)d_in[8];
    const float* c2p_wk  = (const float*)d_in[9];
    const float* c2p_wv  = (const float*)d_in[10];
    const float* c2p_wo  = (const float*)d_in[11];
    const float* w1      = (const float*)d_in[12];
    const float* b1      = (const float*)d_in[13];
    const float* w2      = (const float*)d_in[14];
    const float* b2p     = (const float*)d_in[15];
    const float* lng     = (const float*)d_in[16];
    const float* lnb     = (const float*)d_in[17];
    // d_in[18..20]: gat_iter=2, padding_idx=0, n_heads=8 (hard-coded)

    float* out      = (float*)d_out;
    float* out_ctx  = out + BB * PP * HH;                       // para_context
    float* out_clus = out + BB * PP * HH + BB * PP * TT * HH;   // cluster_state

    k_prep<<<dim3(704), dim3(256), 0, stream>>>(w1, w2,
        p2c_wq, p2c_wk, p2c_wv, p2c_wo, c2p_wq, c2p_wk, c2p_wv, c2p_wo,
        src, cluster, emb);
    k_gat<<<dim3(BB), dim3(512), 0, stream>>>(edge, out, out_clus);
    k_ffn_mfma<<<dim3(256), dim3(256), 0, stream>>>(src, emb, b1, b2p, lng, lnb, out_ctx);
}

// Round 9
// 282.437 us; speedup vs baseline: 2.7720x; 1.0044x over previous
//
#include <hip/hip_runtime.h>
#include <hip/hip_bf16.h>

// Problem constants (fixed by setup_inputs):
#define BB 4
#define PP 32
#define TT 128
#define CC 16
#define TCC 64
#define HH 256
#define NHH 8
#define DD 32      // HH / NHH
#define FFF 1024
// gat_iter=2, padding_idx=0, n_heads=8 hard-coded.
// Inputs fp32, output fp32 (established; rounds 4-8 passed).

typedef __attribute__((ext_vector_type(8))) short bh8;    // 8 bf16 (4 VGPRs)
typedef __attribute__((ext_vector_type(4))) float f32x4;  // MFMA C/D

// Device-global scratch (fully rewritten before read every launch).
__device__ float g_para_feat [BB * PP * HH];
__device__ float g_clus_feat [BB * CC * HH];
__device__ float g_para_state[BB * PP * HH];
// FFN weights, fragment-packed bf16, chunk-contiguous (16 chunks x 64 cols):
// g_w1p: [c][kk(8)][nt(4)][lane(64)][j(8)]
// g_w2p: [c][kk2(2)][nt2(16)][lane(64)][j(8)]
__device__ __align__(16) short g_w1p[HH * FFF];
__device__ __align__(16) short g_w2p[FFF * HH];
// GAT weights: 8 matrices (p2c wq,wk,wv,wo, c2p wq,wk,wv,wo), each
// [kk(8)][nt(16)][lane(64)][j(8)]  (B-frag: B[k=kk*32+quad*8+j][n=nt*16+col])
__device__ __align__(16) short g_gatw[8 * HH * HH];

__device__ __forceinline__ short f2b(float f) {
    union { __hip_bfloat16 h; short s; } u;
    u.h = __float2bfloat16(f);
    return u.s;
}
__device__ __forceinline__ float bs2f(short s) {
    union { float f; unsigned u; } x;
    x.u = ((unsigned)(unsigned short)s) << 16;
    return x.f;
}

// ---------------------------------------------------------------------------
// k_prep: [0,256) pack W1/W2; [256,448) encode feats; [448,704) pack GAT Ws.
// ---------------------------------------------------------------------------
__global__ void __launch_bounds__(256) k_prep(
        const float* __restrict__ w1, const float* __restrict__ w2,
        const float* __restrict__ pq, const float* __restrict__ pk,
        const float* __restrict__ pv, const float* __restrict__ po,
        const float* __restrict__ cq, const float* __restrict__ ck,
        const float* __restrict__ cv, const float* __restrict__ co,
        const int* __restrict__ src, const int* __restrict__ cluster,
        const float* __restrict__ emb) {
    int tid = threadIdx.x;
    if (blockIdx.x < 256) {
        int idx = blockIdx.x * 256 + tid;
        int lane = idx & 63, quad = (lane >> 4) & 3, col = lane & 15;
        if (idx < 32768) {                   // W1 frags
            int f = idx >> 6;
            int nt = f & 3, kk = (f >> 2) & 7, c = f >> 5;
            short* dst = g_w1p + (size_t)idx * 8;
            int n = c * 64 + nt * 16 + col;
            #pragma unroll
            for (int j = 0; j < 8; j++)
                dst[j] = f2b(w1[(kk * 32 + quad * 8 + j) * FFF + n]);
        } else {                             // W2 frags
            int id2 = idx - 32768;
            int f = id2 >> 6;
            int nt2 = f & 15, kk2 = (f >> 4) & 1, c = f >> 5;
            short* dst = g_w2p + (size_t)id2 * 8;
            int n = nt2 * 16 + col;
            #pragma unroll
            for (int j = 0; j < 8; j++)
                dst[j] = f2b(w2[(c * 64 + kk2 * 32 + quad * 8 + j) * HH + n]);
        }
    } else if (blockIdx.x < 448) {
        int bid = blockIdx.x - 256;
        __shared__ int stok[TT];
        if (bid < BB * PP) {
            if (tid < TT) stok[tid] = src[bid * TT + tid];
            __syncthreads();
            float acc = 0.f; int cnt = 0;
            #pragma unroll 8
            for (int i = 0; i < TT; i++) {
                int tk = stok[i];
                if (tk != 0) { cnt++; acc += emb[(size_t)tk * HH + tid]; }
            }
            g_para_feat[bid * HH + tid] = acc / fmaxf((float)cnt, 1.0f);
        } else {
            int cid = bid - BB * PP;
            if (tid < TCC) stok[tid] = cluster[cid * TCC + tid];
            __syncthreads();
            float acc = 0.f; int cnt = 0;
            #pragma unroll 8
            for (int i = 0; i < TCC; i++) {
                int tk = stok[i];
                if (tk != 0) { cnt++; acc += emb[(size_t)tk * HH + tid]; }
            }
            g_clus_feat[cid * HH + tid] = acc / fmaxf((float)cnt, 1.0f);
        }
    } else {
        int pid = blockIdx.x - 448;          // 0..255
        int mat = pid >> 5;                  // 0..7
        int gi = (pid & 31) * 256 + tid;     // granule 0..8191
        int lane = gi & 63, quad = (lane >> 4) & 3, col = lane & 15;
        int f = gi >> 6;                     // 0..127
        int nt = f & 15, kk = f >> 4;
        const float* ws = (mat == 0) ? pq : (mat == 1) ? pk : (mat == 2) ? pv :
                          (mat == 3) ? po : (mat == 4) ? cq : (mat == 5) ? ck :
                          (mat == 6) ? cv : co;
        short* dst = g_gatw + ((size_t)mat * 8192 + gi) * 8;
        int n = nt * 16 + col;
        #pragma unroll
        for (int j = 0; j < 8; j++)
            dst[j] = f2b(ws[(kk * 32 + quad * 8 + j) * HH + n]);
    }
}

// ---------------------------------------------------------------------------
// GAT layer, all-MFMA, compile-time-unrolled job loops (ILP across jobs).
// 512 threads = 8 waves. mfma_f32_16x16x32_bf16 layouts per §3.
// ---------------------------------------------------------------------------
template<int NQ, int NK>
__device__ void gat_layer(int tid,
                          float (*__restrict__ qs)[264], short (*__restrict__ qsb)[264],
                          short (*__restrict__ kvb)[264],
                          const short* __restrict__ wm,
                          const int* __restrict__ msk, const int* __restrict__ has,
                          short (*__restrict__ s_q)[264],   // also reused as O
                          short (*__restrict__ s_k)[264],
                          short (*__restrict__ s_vT)[44],
                          short (*__restrict__ s_pb)[32][44]) {
    constexpr int MTQ = NQ / 16, MTK = NK / 16;
    int w = tid >> 6, lane = tid & 63, quad = (lane >> 4) & 3, col = lane & 15;

    // ---- Phase 1: q/k/v projections ----
    constexpr int NI1 = ((MTQ + 2 * MTK) * 16) / 8;
    #pragma unroll
    for (int it = 0; it < NI1; it++) {
        int jid = it * 8 + w;
        int nt = jid & 15, t = jid >> 4;
        int mi, mt;
        if (t < MTQ)            { mi = 0; mt = t; }
        else if (t < MTQ + MTK) { mi = 1; mt = t - MTQ; }
        else                    { mi = 2; mt = t - MTQ - MTK; }
        const short (*Ab)[264] = (mi == 0) ? qsb : kvb;
        const short* bb = wm + mi * 65536;
        f32x4 acc = (f32x4){0.f, 0.f, 0.f, 0.f};
        #pragma unroll
        for (int kk = 0; kk < 8; kk++) {
            bh8 a = *(const bh8*)&Ab[mt * 16 + col][kk * 32 + quad * 8];
            bh8 bf = *(const bh8*)(bb + ((kk * 16 + nt) * 64 + lane) * 8);
            acc = __builtin_amdgcn_mfma_f32_16x16x32_bf16(a, bf, acc, 0, 0, 0);
        }
        #pragma unroll
        for (int r = 0; r < 4; r++) {
            int row = mt * 16 + quad * 4 + r, n = nt * 16 + col;
            if (mi == 0)      s_q[row][n] = f2b(acc[r]);
            else if (mi == 1) s_k[row][n] = f2b(acc[r]);
            else              s_vT[n][row] = f2b(acc[r]);     // transposed
        }
    }
    if (NK == 16) {     // zero vT pad rows [16,32) so P@V pad contributes 0
        int d = tid >> 1, o = 16 + (tid & 1) * 8;
        #pragma unroll
        for (int j = 0; j < 8; j++) s_vT[d][o + j] = 0;
    }
    __syncthreads();

    // ---- Phase 2: scores = Q_h @ K_h^T (per head), mask, scale ----
    constexpr int NI2 = (8 * MTQ * MTK) / 8;
    #pragma unroll
    for (int it = 0; it < NI2; it++) {
        int jid = it * 8 + w;
        int h = jid & 7, rest = jid >> 3;
        int mt = rest % MTQ, nt = rest / MTQ;
        bh8 a  = *(const bh8*)&s_q[mt * 16 + col][h * 32 + quad * 8];
        bh8 bf = *(const bh8*)&s_k[nt * 16 + col][h * 32 + quad * 8];
        f32x4 acc = (f32x4){0.f, 0.f, 0.f, 0.f};
        acc = __builtin_amdgcn_mfma_f32_16x16x32_bf16(a, bf, acc, 0, 0, 0);
        #pragma unroll
        for (int r = 0; r < 4; r++) {
            int qrow = mt * 16 + quad * 4 + r, krow = nt * 16 + col;
            int bit = (msk[qrow] >> krow) & 1;
            s_pb[h][qrow][krow] = f2b(bit ? acc[r] * 0.17677669529663687f : -1e9f);
        }
    }
    __syncthreads();

    // ---- Phase 3: softmax per (qi, h), write normalized P (bf16, pad->0) ----
    if (tid < NQ * 8) {
        int qi = tid >> 3, h = tid & 7;
        float av[NK]; float mx = -1e30f;
        #pragma unroll
        for (int k = 0; k < NK; k++) { av[k] = bs2f(s_pb[h][qi][k]); mx = fmaxf(mx, av[k]); }
        float sm = 0.f;
        #pragma unroll
        for (int k = 0; k < NK; k++) { av[k] = __expf(av[k] - mx); sm += av[k]; }
        float inv = 1.f / sm;
        #pragma unroll
        for (int k = 0; k < NK; k++) s_pb[h][qi][k] = f2b(av[k] * inv);
        if (NK == 16) {
            #pragma unroll
            for (int k = 16; k < 32; k++) s_pb[h][qi][k] = 0;
        }
    }
    __syncthreads();

    // ---- Phase 4: O_h = P_h @ V_h  -> s_q reused as O ----
    constexpr int NI4 = (8 * MTQ * 2) / 8;
    #pragma unroll
    for (int it = 0; it < NI4; it++) {
        int jid = it * 8 + w;
        int h = jid & 7, rest = jid >> 3;
        int mt = rest % MTQ, nt2 = rest / MTQ;
        bh8 a  = *(const bh8*)&s_pb[h][mt * 16 + col][quad * 8];
        bh8 bf = *(const bh8*)&s_vT[h * 32 + nt2 * 16 + col][quad * 8];
        f32x4 acc = (f32x4){0.f, 0.f, 0.f, 0.f};
        acc = __builtin_amdgcn_mfma_f32_16x16x32_bf16(a, bf, acc, 0, 0, 0);
        #pragma unroll
        for (int r = 0; r < 4; r++)
            s_q[mt * 16 + quad * 4 + r][h * 32 + nt2 * 16 + col] = f2b(acc[r]);
    }
    __syncthreads();

    // ---- Phase 5: out = O @ wo ; qs += hasnb * out ; refresh bf16 mirror ----
    constexpr int NI5 = (MTQ * 16) / 8;
    #pragma unroll
    for (int it = 0; it < NI5; it++) {
        int jid = it * 8 + w;
        int nt = jid & 15, mt = jid >> 4;
        const short* bb = wm + 3 * 65536;
        f32x4 acc = (f32x4){0.f, 0.f, 0.f, 0.f};
        #pragma unroll
        for (int kk = 0; kk < 8; kk++) {
            bh8 a = *(const bh8*)&s_q[mt * 16 + col][kk * 32 + quad * 8];
            bh8 bf = *(const bh8*)(bb + ((kk * 16 + nt) * 64 + lane) * 8);
            acc = __builtin_amdgcn_mfma_f32_16x16x32_bf16(a, bf, acc, 0, 0, 0);
        }
        #pragma unroll
        for (int r = 0; r < 4; r++) {
            int row = mt * 16 + quad * 4 + r, n = nt * 16 + col;
            float nv = qs[row][n] + (has[row] ? acc[r] : 0.f);
            qs[row][n] = nv;
            qsb[row][n] = f2b(nv);
        }
    }
    __syncthreads();
}

// ---------------------------------------------------------------------------
// k_gat: whole 5-layer chain, 1 block/batch, 512 threads, states in LDS.
// ---------------------------------------------------------------------------
__global__ void __launch_bounds__(512) k_gat(const int* __restrict__ edge,
                                             float* __restrict__ out_ps,
                                             float* __restrict__ out_cs) {
    __shared__ __align__(16) float s_ps [PP][264];
    __shared__ __align__(16) float s_cs [CC][264];
    __shared__ __align__(16) short s_psb[PP][264];
    __shared__ __align__(16) short s_csb[CC][264];
    __shared__ __align__(16) short s_q  [PP][264];
    __shared__ __align__(16) short s_k  [PP][264];
    __shared__ __align__(16) short s_vT [HH][44];
    __shared__ __align__(16) short s_pb [NHH][32][44];
    __shared__ int s_mskP[PP], s_hasP[PP], s_mskC[CC], s_hasC[CC];

    int b = blockIdx.x, tid = threadIdx.x;
    const int* eb = edge + b * PP * CC;

    #pragma unroll
    for (int rep = 0; rep < 16; rep++) {
        int idx = rep * 512 + tid;
        float v = g_para_feat[b * PP * HH + idx];
        s_ps[idx >> 8][idx & 255] = v;
        s_psb[idx >> 8][idx & 255] = f2b(v);
    }
    #pragma unroll
    for (int rep = 0; rep < 8; rep++) {
        int idx = rep * 512 + tid;
        float v = g_clus_feat[b * CC * HH + idx];
        s_cs[idx >> 8][idx & 255] = v;
        s_csb[idx >> 8][idx & 255] = f2b(v);
    }
    if (tid < PP) {
        int m = 0;
        #pragma unroll
        for (int k = 0; k < CC; k++) m |= (eb[tid * CC + k] > 0) << k;
        s_mskP[tid] = m; s_hasP[tid] = (m != 0);
    } else if (tid < PP + CC) {
        int ci = tid - PP, m = 0;
        #pragma unroll
        for (int p = 0; p < PP; p++) m |= (eb[p * CC + ci] > 0) << p;
        s_mskC[ci] = m; s_hasC[ci] = (m != 0);
    }
    __syncthreads();

    const short* wmp = g_gatw;                 // p2c set
    const short* wmc = g_gatw + 4 * 65536;     // c2p set

    gat_layer<PP, CC>(tid, s_ps, s_psb, s_csb, wmp, s_mskP, s_hasP, s_q, s_k, s_vT, s_pb);
    gat_layer<CC, PP>(tid, s_cs, s_csb, s_psb, wmc, s_mskC, s_hasC, s_q, s_k, s_vT, s_pb);
    gat_layer<PP, CC>(tid, s_ps, s_psb, s_csb, wmp, s_mskP, s_hasP, s_q, s_k, s_vT, s_pb);
    gat_layer<CC, PP>(tid, s_cs, s_csb, s_psb, wmc, s_mskC, s_hasC, s_q, s_k, s_vT, s_pb);
    gat_layer<PP, CC>(tid, s_ps, s_psb, s_csb, wmp, s_mskP, s_hasP, s_q, s_k, s_vT, s_pb);

    #pragma unroll
    for (int rep = 0; rep < 16; rep++) {
        int idx = rep * 512 + tid;
        float v = s_ps[idx >> 8][idx & 255];
        out_ps[b * PP * HH + idx] = v;
        g_para_state[b * PP * HH + idx] = v;
    }
    #pragma unroll
    for (int rep = 0; rep < 8; rep++) {
        int idx = rep * 512 + tid;
        out_cs[b * CC * HH + idx] = s_cs[idx >> 8][idx & 255];
    }
}

// ---------------------------------------------------------------------------
// FFN v5: 64 tokens/block, grid 256, 4 waves = (strip-pair sh, col-half ch).
// x = emb+ps loaded ONCE coalesced into persistent LDS xf (fp32); LN stats,
// normalize, and epilogue residual all come from LDS — no scattered global
// gathers. B-frags from L2 in independent batches. LDS ~112 KB.
// ---------------------------------------------------------------------------
__global__ void __launch_bounds__(256, 1) k_ffn_mfma(
        const int* __restrict__ src, const float* __restrict__ emb,
        const float* __restrict__ b1, const float* __restrict__ b2v,
        const float* __restrict__ lng, const float* __restrict__ lnb,
        float* __restrict__ out_ctx) {
    __shared__ __align__(16) float xf[64 * 260];    // 66.6 KB, row stride 260
    __shared__ __align__(16) short xn[64][264];     // 33.8 KB
    __shared__ __align__(16) short sbuf[64][72];    // 9.2 KB
    __shared__ float red_s[64][4], red_s2[64][4];
    __shared__ float mu[64], rsd[64];
    __shared__ int   toks[64];

    int tid = threadIdx.x;
    int t0 = blockIdx.x * 64;
    int pr = blockIdx.x >> 1;
    const float* psr = g_para_state + pr * HH;

    if (tid < 64) toks[tid] = src[t0 + tid];
    __syncthreads();

    {   // ph1: coalesced x = emb+ps -> xf (thread owns dim tid; 1 row/iter)
        float psv = psr[tid];
        #pragma unroll 8
        for (int m = 0; m < 64; m++) {
            int tk = toks[m];
            float x = (tk ? emb[(size_t)tk * HH + tid] : 0.f) + psv;
            xf[m * 260 + tid] = x;
        }
    }
    __syncthreads();
    {   // ph2: LN stats from LDS. thread (m, q) sums dims d = j*4+q (2-way banks)
        int m = tid >> 2, q = tid & 3;
        float s = 0.f, s2 = 0.f;
        #pragma unroll
        for (int j = 0; j < 64; j++) {
            float v = xf[m * 260 + j * 4 + q];
            s += v; s2 += v * v;
        }
        red_s[m][q] = s; red_s2[m][q] = s2;
    }
    __syncthreads();
    if (tid < 64) {
        float s  = red_s [tid][0] + red_s [tid][1] + red_s [tid][2] + red_s [tid][3];
        float s2 = red_s2[tid][0] + red_s2[tid][1] + red_s2[tid][2] + red_s2[tid][3];
        float mean = s * (1.f / HH);
        float var  = s2 * (1.f / HH) - mean * mean;
        mu[tid] = mean; rsd[tid] = rsqrtf(var + 1e-6f);
    }
    __syncthreads();
    {   // ph3: normalize from LDS -> xn bf16
        float g = lng[tid], bt = lnb[tid];
        #pragma unroll 8
        for (int m = 0; m < 64; m++)
            xn[m][tid] = f2b((xf[m * 260 + tid] - mu[m]) * rsd[m] * g + bt);
    }
    __syncthreads();

    int wv = tid >> 6, lane = tid & 63, quad = (lane >> 4) & 3, col = lane & 15;
    int sh = wv & 1, ch = wv >> 1;

    f32x4 acc2[2][8];
    #pragma unroll
    for (int si = 0; si < 2; si++)
        #pragma unroll
        for (int j2 = 0; j2 < 8; j2++) acc2[si][j2] = (f32x4){0.f, 0.f, 0.f, 0.f};

    for (int c = 0; c < 16; c++) {
        // GEMM1: B1 = 16 frags from L2 (independent batch)
        bh8 B1[8][2];
        #pragma unroll
        for (int kk = 0; kk < 8; kk++)
            #pragma unroll
            for (int nt = 0; nt < 2; nt++)
                B1[kk][nt] = *(const bh8*)(g_w1p +
                    (((size_t)(c * 8 + kk) * 4 + ch * 2 + nt) * 64 + lane) * 8);
        f32x4 acc1[2][2];
        #pragma unroll
        for (int si = 0; si < 2; si++)
            #pragma unroll
            for (int nt = 0; nt < 2; nt++) acc1[si][nt] = (f32x4){0.f, 0.f, 0.f, 0.f};
        #pragma unroll
        for (int kk = 0; kk < 8; kk++) {
            #pragma unroll
            for (int si = 0; si < 2; si++) {
                bh8 a = *(const bh8*)&xn[(sh * 2 + si) * 16 + col][kk * 32 + quad * 8];
                acc1[si][0] = __builtin_amdgcn_mfma_f32_16x16x32_bf16(a, B1[kk][0], acc1[si][0], 0, 0, 0);
                acc1[si][1] = __builtin_amdgcn_mfma_f32_16x16x32_bf16(a, B1[kk][1], acc1[si][1], 0, 0, 0);
            }
        }
        // B2 for this chunk (issued early; latency hidden by relu+barrier)
        bh8 B2[2][8];
        #pragma unroll
        for (int kk2 = 0; kk2 < 2; kk2++)
            #pragma unroll
            for (int j2 = 0; j2 < 8; j2++)
                B2[kk2][j2] = *(const bh8*)(g_w2p +
                    (((size_t)(c * 2 + kk2) * 16 + ch * 8 + j2) * 64 + lane) * 8);
        // bias + relu -> sbuf
        #pragma unroll
        for (int si = 0; si < 2; si++)
            #pragma unroll
            for (int nt = 0; nt < 2; nt++) {
                float bias = b1[c * 64 + ch * 32 + nt * 16 + col];
                #pragma unroll
                for (int r = 0; r < 4; r++) {
                    float v = acc1[si][nt][r] + bias;
                    sbuf[(sh * 2 + si) * 16 + quad * 4 + r][ch * 32 + nt * 16 + col] =
                        f2b(v > 0.f ? v : 0.f);
                }
            }
        __syncthreads();
        // GEMM2 over this chunk's 64 K-dims
        #pragma unroll
        for (int kk2 = 0; kk2 < 2; kk2++) {
            #pragma unroll
            for (int si = 0; si < 2; si++) {
                bh8 a2 = *(const bh8*)&sbuf[(sh * 2 + si) * 16 + col][kk2 * 32 + quad * 8];
                #pragma unroll
                for (int j2 = 0; j2 < 8; j2++)
                    acc2[si][j2] = __builtin_amdgcn_mfma_f32_16x16x32_bf16(a2, B2[kk2][j2], acc2[si][j2], 0, 0, 0);
            }
        }
        __syncthreads();
    }

    // Epilogue: + b2 + residual from LDS xf (fp32-exact), mask, store
    #pragma unroll
    for (int j2 = 0; j2 < 8; j2++) {
        int n = ch * 128 + j2 * 16 + col;
        float bias = b2v[n];
        #pragma unroll
        for (int si = 0; si < 2; si++)
            #pragma unroll
            for (int r = 0; r < 4; r++) {
                int ml = (sh * 2 + si) * 16 + quad * 4 + r;
                int gt = t0 + ml;
                int tk = toks[ml];
                float x = xf[ml * 260 + n];
                out_ctx[(size_t)gt * HH + n] = tk ? (acc2[si][j2][r] + bias + x) : 0.f;
            }
    }
}

// ---------------------------------------------------------------------------
extern "C" void kernel_launch(void* const* d_in, const int* in_sizes, int n_in,
                              void* d_out, int out_size, void* d_ws, size_t ws_size,
                              hipStream_t stream) {
    const int*   src     = (const int*)d_in[0];
    const int*   cluster = (const int*)d_in[1];
    const int*   edge    = (const int*)d_in[2];
    const float* emb     = (const float*)d_in[3];
    const float* p2c_wq  = (const float*)d_in[4];
    const float* p2c_wk  = (const float*)d_in[5];
    const float* p2c_wv  = (const float*)d_in[6];
    const float* p2c_wo  = (const float*)d_in[7];
    const float* c2p_wq  = (const float*)d_in[8];
    const float* c2p_wk  = (const float*)d_in[9];
    const float* c2p_wv  = (const float*)d_in[10];
    const float* c2p_wo  = (const float*)d_in[11];
    const float* w1      = (const float*)d_in[12];
    const float* b1      = (const float*)d_in[13];
    const float* w2      = (const float*)d_in[14];
    const float* b2p     = (const float*)d_in[15];
    const float* lng     = (const float*)d_in[16];
    const float* lnb     = (const float*)d_in[17];
    // d_in[18..20]: gat_iter=2, padding_idx=0, n_heads=8 (hard-coded)

    float* out      = (float*)d_out;
    float* out_ctx  = out + BB * PP * HH;                       // para_context
    float* out_clus = out + BB * PP * HH + BB * PP * TT * HH;   // cluster_state

    k_prep<<<dim3(704), dim3(256), 0, stream>>>(w1, w2,
        p2c_wq, p2c_wk, p2c_wv, p2c_wo, c2p_wq, c2p_wk, c2p_wv, c2p_wo,
        src, cluster, emb);
    k_gat<<<dim3(BB), dim3(512), 0, stream>>>(edge, out, out_clus);
    k_ffn_mfma<<<dim3(256), dim3(256), 0, stream>>>(src, emb, b1, b2p, lng, lnb, out_ctx);
}

// Round 10
// 272.893 us; speedup vs baseline: 2.8689x; 1.0350x over previous
//
#include <hip/hip_runtime.h>
#include <hip/hip_bf16.h>

// Problem constants (fixed by setup_inputs):
#define BB 4
#define PP 32
#define TT 128
#define CC 16
#define TCC 64
#define HH 256
#define NHH 8
#define DD 32      // HH / NHH
#define FFF 1024
// gat_iter=2, padding_idx=0, n_heads=8 hard-coded.
// Inputs fp32, output fp32 (established; rounds 4-9 passed).

typedef __attribute__((ext_vector_type(8))) short bh8;    // 8 bf16 (4 VGPRs)
typedef __attribute__((ext_vector_type(4))) float f32x4;  // MFMA C/D

// Device-global scratch (fully rewritten before read every launch).
__device__ float g_para_feat [BB * PP * HH];
__device__ float g_clus_feat [BB * CC * HH];
__device__ float g_para_state[BB * PP * HH];
// FFN weights, fragment-packed bf16, 32 chunks of 32 hidden cols, chunk-contig:
// g_w1p granule idx = ((c*8+kk)*2+nt)*64+lane : w1[k=kk*32+quad*8+j][n=c*32+nt*16+col]
// g_w2p granule idx = (c*16+nt2)*64+lane      : w2[k=c*32+quad*8+j][n=nt2*16+col]
__device__ __align__(16) short g_w1p[HH * FFF];
__device__ __align__(16) short g_w2p[FFF * HH];
// GAT weights: 8 matrices (p2c wq,wk,wv,wo, c2p wq,wk,wv,wo), each
// [kk(8)][nt(16)][lane(64)][j(8)]  (B-frag: B[k=kk*32+quad*8+j][n=nt*16+col])
__device__ __align__(16) short g_gatw[8 * HH * HH];

__device__ __forceinline__ short f2b(float f) {
    union { __hip_bfloat16 h; short s; } u;
    u.h = __float2bfloat16(f);
    return u.s;
}
__device__ __forceinline__ float bs2f(short s) {
    union { float f; unsigned u; } x;
    x.u = ((unsigned)(unsigned short)s) << 16;
    return x.f;
}

// ---------------------------------------------------------------------------
// k_prep: [0,256) pack W1/W2; [256,448) encode feats; [448,704) pack GAT Ws.
// ---------------------------------------------------------------------------
__global__ void __launch_bounds__(256) k_prep(
        const float* __restrict__ w1, const float* __restrict__ w2,
        const float* __restrict__ pq, const float* __restrict__ pk,
        const float* __restrict__ pv, const float* __restrict__ po,
        const float* __restrict__ cq, const float* __restrict__ ck,
        const float* __restrict__ cv, const float* __restrict__ co,
        const int* __restrict__ src, const int* __restrict__ cluster,
        const float* __restrict__ emb) {
    int tid = threadIdx.x;
    if (blockIdx.x < 256) {
        int idx = blockIdx.x * 256 + tid;
        int lane = idx & 63, quad = (lane >> 4) & 3, col = lane & 15;
        if (idx < 32768) {                   // W1 granules
            int f = idx >> 6;                // 0..511
            int nt = f & 1, kk = (f >> 1) & 7, c = f >> 4;
            short* dst = g_w1p + (size_t)idx * 8;
            int n = c * 32 + nt * 16 + col;
            #pragma unroll
            for (int j = 0; j < 8; j++)
                dst[j] = f2b(w1[(kk * 32 + quad * 8 + j) * FFF + n]);
        } else {                             // W2 granules
            int id2 = idx - 32768;
            int f = id2 >> 6;                // 0..511
            int nt2 = f & 15, c = f >> 4;
            short* dst = g_w2p + (size_t)id2 * 8;
            int n = nt2 * 16 + col;
            #pragma unroll
            for (int j = 0; j < 8; j++)
                dst[j] = f2b(w2[(c * 32 + quad * 8 + j) * HH + n]);
        }
    } else if (blockIdx.x < 448) {
        int bid = blockIdx.x - 256;
        __shared__ int stok[TT];
        if (bid < BB * PP) {
            if (tid < TT) stok[tid] = src[bid * TT + tid];
            __syncthreads();
            float acc = 0.f; int cnt = 0;
            #pragma unroll 8
            for (int i = 0; i < TT; i++) {
                int tk = stok[i];
                if (tk != 0) { cnt++; acc += emb[(size_t)tk * HH + tid]; }
            }
            g_para_feat[bid * HH + tid] = acc / fmaxf((float)cnt, 1.0f);
        } else {
            int cid = bid - BB * PP;
            if (tid < TCC) stok[tid] = cluster[cid * TCC + tid];
            __syncthreads();
            float acc = 0.f; int cnt = 0;
            #pragma unroll 8
            for (int i = 0; i < TCC; i++) {
                int tk = stok[i];
                if (tk != 0) { cnt++; acc += emb[(size_t)tk * HH + tid]; }
            }
            g_clus_feat[cid * HH + tid] = acc / fmaxf((float)cnt, 1.0f);
        }
    } else {
        int pid = blockIdx.x - 448;          // 0..255
        int mat = pid >> 5;                  // 0..7
        int gi = (pid & 31) * 256 + tid;     // granule 0..8191
        int lane = gi & 63, quad = (lane >> 4) & 3, col = lane & 15;
        int f = gi >> 6;                     // 0..127
        int nt = f & 15, kk = f >> 4;
        const float* ws = (mat == 0) ? pq : (mat == 1) ? pk : (mat == 2) ? pv :
                          (mat == 3) ? po : (mat == 4) ? cq : (mat == 5) ? ck :
                          (mat == 6) ? cv : co;
        short* dst = g_gatw + ((size_t)mat * 8192 + gi) * 8;
        int n = nt * 16 + col;
        #pragma unroll
        for (int j = 0; j < 8; j++)
            dst[j] = f2b(ws[(kk * 32 + quad * 8 + j) * HH + n]);
    }
}

// ---------------------------------------------------------------------------
// GAT layer, all-MFMA. 1024 threads = 16 waves share balanced job lists.
// ---------------------------------------------------------------------------
template<int NQ, int NK>
__device__ void gat_layer(int tid,
                          float (*__restrict__ qs)[264], short (*__restrict__ qsb)[264],
                          short (*__restrict__ kvb)[264],
                          const short* __restrict__ wm,
                          const int* __restrict__ msk, const int* __restrict__ has,
                          short (*__restrict__ s_q)[264],   // also reused as O
                          short (*__restrict__ s_k)[264],
                          short (*__restrict__ s_vT)[44],
                          short (*__restrict__ s_pb)[32][44]) {
    constexpr int MTQ = NQ / 16, MTK = NK / 16;
    int w = tid >> 6, lane = tid & 63, quad = (lane >> 4) & 3, col = lane & 15;

    // ---- Phase 1: q/k/v projections ----
    constexpr int NI1 = ((MTQ + 2 * MTK) * 16) / 16;
    #pragma unroll
    for (int it = 0; it < NI1; it++) {
        int jid = it * 16 + w;
        int nt = jid & 15, t = jid >> 4;
        int mi, mt;
        if (t < MTQ)            { mi = 0; mt = t; }
        else if (t < MTQ + MTK) { mi = 1; mt = t - MTQ; }
        else                    { mi = 2; mt = t - MTQ - MTK; }
        const short (*Ab)[264] = (mi == 0) ? qsb : kvb;
        const short* bb = wm + mi * 65536;
        f32x4 acc = (f32x4){0.f, 0.f, 0.f, 0.f};
        #pragma unroll
        for (int kk = 0; kk < 8; kk++) {
            bh8 a = *(const bh8*)&Ab[mt * 16 + col][kk * 32 + quad * 8];
            bh8 bf = *(const bh8*)(bb + ((kk * 16 + nt) * 64 + lane) * 8);
            acc = __builtin_amdgcn_mfma_f32_16x16x32_bf16(a, bf, acc, 0, 0, 0);
        }
        #pragma unroll
        for (int r = 0; r < 4; r++) {
            int row = mt * 16 + quad * 4 + r, n = nt * 16 + col;
            if (mi == 0)      s_q[row][n] = f2b(acc[r]);
            else if (mi == 1) s_k[row][n] = f2b(acc[r]);
            else              s_vT[n][row] = f2b(acc[r]);     // transposed
        }
    }
    if (NK == 16 && tid < 512) {  // zero vT pad rows [16,32)
        int d = tid >> 1, o = 16 + (tid & 1) * 8;
        #pragma unroll
        for (int j = 0; j < 8; j++) s_vT[d][o + j] = 0;
    }
    __syncthreads();

    // ---- Phase 2: scores = Q_h @ K_h^T (per head), mask, scale ----
    constexpr int NI2 = (8 * MTQ * MTK) / 16;
    #pragma unroll
    for (int it = 0; it < NI2; it++) {
        int jid = it * 16 + w;
        int h = jid & 7, rest = jid >> 3;
        int mt = rest % MTQ, nt = rest / MTQ;
        bh8 a  = *(const bh8*)&s_q[mt * 16 + col][h * 32 + quad * 8];
        bh8 bf = *(const bh8*)&s_k[nt * 16 + col][h * 32 + quad * 8];
        f32x4 acc = (f32x4){0.f, 0.f, 0.f, 0.f};
        acc = __builtin_amdgcn_mfma_f32_16x16x32_bf16(a, bf, acc, 0, 0, 0);
        #pragma unroll
        for (int r = 0; r < 4; r++) {
            int qrow = mt * 16 + quad * 4 + r, krow = nt * 16 + col;
            int bit = (msk[qrow] >> krow) & 1;
            s_pb[h][qrow][krow] = f2b(bit ? acc[r] * 0.17677669529663687f : -1e9f);
        }
    }
    __syncthreads();

    // ---- Phase 3: softmax per (qi, h), write normalized P (bf16, pad->0) ----
    if (tid < NQ * 8) {
        int qi = tid >> 3, h = tid & 7;
        float av[NK]; float mx = -1e30f;
        #pragma unroll
        for (int k = 0; k < NK; k++) { av[k] = bs2f(s_pb[h][qi][k]); mx = fmaxf(mx, av[k]); }
        float sm = 0.f;
        #pragma unroll
        for (int k = 0; k < NK; k++) { av[k] = __expf(av[k] - mx); sm += av[k]; }
        float inv = 1.f / sm;
        #pragma unroll
        for (int k = 0; k < NK; k++) s_pb[h][qi][k] = f2b(av[k] * inv);
        if (NK == 16) {
            #pragma unroll
            for (int k = 16; k < 32; k++) s_pb[h][qi][k] = 0;
        }
    }
    __syncthreads();

    // ---- Phase 4: O_h = P_h @ V_h  -> s_q reused as O ----
    constexpr int NI4 = (8 * MTQ * 2) / 16;
    #pragma unroll
    for (int it = 0; it < NI4; it++) {
        int jid = it * 16 + w;
        int h = jid & 7, rest = jid >> 3;
        int mt = rest % MTQ, nt2 = rest / MTQ;
        bh8 a  = *(const bh8*)&s_pb[h][mt * 16 + col][quad * 8];
        bh8 bf = *(const bh8*)&s_vT[h * 32 + nt2 * 16 + col][quad * 8];
        f32x4 acc = (f32x4){0.f, 0.f, 0.f, 0.f};
        acc = __builtin_amdgcn_mfma_f32_16x16x32_bf16(a, bf, acc, 0, 0, 0);
        #pragma unroll
        for (int r = 0; r < 4; r++)
            s_q[mt * 16 + quad * 4 + r][h * 32 + nt2 * 16 + col] = f2b(acc[r]);
    }
    __syncthreads();

    // ---- Phase 5: out = O @ wo ; qs += hasnb * out ; refresh bf16 mirror ----
    constexpr int NI5 = (MTQ * 16) / 16;
    #pragma unroll
    for (int it = 0; it < NI5; it++) {
        int jid = it * 16 + w;
        int nt = jid & 15, mt = jid >> 4;
        const short* bb = wm + 3 * 65536;
        f32x4 acc = (f32x4){0.f, 0.f, 0.f, 0.f};
        #pragma unroll
        for (int kk = 0; kk < 8; kk++) {
            bh8 a = *(const bh8*)&s_q[mt * 16 + col][kk * 32 + quad * 8];
            bh8 bf = *(const bh8*)(bb + ((kk * 16 + nt) * 64 + lane) * 8);
            acc = __builtin_amdgcn_mfma_f32_16x16x32_bf16(a, bf, acc, 0, 0, 0);
        }
        #pragma unroll
        for (int r = 0; r < 4; r++) {
            int row = mt * 16 + quad * 4 + r, n = nt * 16 + col;
            float nv = qs[row][n] + (has[row] ? acc[r] : 0.f);
            qs[row][n] = nv;
            qsb[row][n] = f2b(nv);
        }
    }
    __syncthreads();
}

// ---------------------------------------------------------------------------
// k_gat: whole 5-layer chain, 1 block/batch, 1024 threads (16 waves).
// ---------------------------------------------------------------------------
__global__ void __launch_bounds__(1024, 4) k_gat(const int* __restrict__ edge,
                                                 float* __restrict__ out_ps,
                                                 float* __restrict__ out_cs) {
    __shared__ __align__(16) float s_ps [PP][264];
    __shared__ __align__(16) float s_cs [CC][264];
    __shared__ __align__(16) short s_psb[PP][264];
    __shared__ __align__(16) short s_csb[CC][264];
    __shared__ __align__(16) short s_q  [PP][264];
    __shared__ __align__(16) short s_k  [PP][264];
    __shared__ __align__(16) short s_vT [HH][44];
    __shared__ __align__(16) short s_pb [NHH][32][44];
    __shared__ int s_mskP[PP], s_hasP[PP], s_mskC[CC], s_hasC[CC];

    int b = blockIdx.x, tid = threadIdx.x;
    const int* eb = edge + b * PP * CC;

    #pragma unroll
    for (int rep = 0; rep < 8; rep++) {
        int idx = rep * 1024 + tid;
        float v = g_para_feat[b * PP * HH + idx];
        s_ps[idx >> 8][idx & 255] = v;
        s_psb[idx >> 8][idx & 255] = f2b(v);
    }
    #pragma unroll
    for (int rep = 0; rep < 4; rep++) {
        int idx = rep * 1024 + tid;
        float v = g_clus_feat[b * CC * HH + idx];
        s_cs[idx >> 8][idx & 255] = v;
        s_csb[idx >> 8][idx & 255] = f2b(v);
    }
    if (tid < PP) {
        int m = 0;
        #pragma unroll
        for (int k = 0; k < CC; k++) m |= (eb[tid * CC + k] > 0) << k;
        s_mskP[tid] = m; s_hasP[tid] = (m != 0);
    } else if (tid < PP + CC) {
        int ci = tid - PP, m = 0;
        #pragma unroll
        for (int p = 0; p < PP; p++) m |= (eb[p * CC + ci] > 0) << p;
        s_mskC[ci] = m; s_hasC[ci] = (m != 0);
    }
    __syncthreads();

    const short* wmp = g_gatw;                 // p2c set
    const short* wmc = g_gatw + 4 * 65536;     // c2p set

    gat_layer<PP, CC>(tid, s_ps, s_psb, s_csb, wmp, s_mskP, s_hasP, s_q, s_k, s_vT, s_pb);
    gat_layer<CC, PP>(tid, s_cs, s_csb, s_psb, wmc, s_mskC, s_hasC, s_q, s_k, s_vT, s_pb);
    gat_layer<PP, CC>(tid, s_ps, s_psb, s_csb, wmp, s_mskP, s_hasP, s_q, s_k, s_vT, s_pb);
    gat_layer<CC, PP>(tid, s_cs, s_csb, s_psb, wmc, s_mskC, s_hasC, s_q, s_k, s_vT, s_pb);
    gat_layer<PP, CC>(tid, s_ps, s_psb, s_csb, wmp, s_mskP, s_hasP, s_q, s_k, s_vT, s_pb);

    #pragma unroll
    for (int rep = 0; rep < 8; rep++) {
        int idx = rep * 1024 + tid;
        float v = s_ps[idx >> 8][idx & 255];
        out_ps[b * PP * HH + idx] = v;
        g_para_state[b * PP * HH + idx] = v;
    }
    #pragma unroll
    for (int rep = 0; rep < 4; rep++) {
        int idx = rep * 1024 + tid;
        out_cs[b * CC * HH + idx] = s_cs[idx >> 8][idx & 255];
    }
}

// ---------------------------------------------------------------------------
// FFN v6: 64 tokens/block, grid 256, 4 waves = (strip-pair sh, col-half ch).
// Per 32-col chunk: stage W1c+W2c (32 KB) into LDS with BATCHED loads, then
// MFMAs feed from ds_read_b128. A1 frags preloaded in 64 VGPRs. LDS ~74 KB.
// ---------------------------------------------------------------------------
__global__ void __launch_bounds__(256, 2) k_ffn_mfma(
        const int* __restrict__ src, const float* __restrict__ emb,
        const float* __restrict__ b1, const float* __restrict__ b2v,
        const float* __restrict__ lng, const float* __restrict__ lnb,
        float* __restrict__ out_ctx) {
    __shared__ __align__(16) short xn[64][264];     // 33.8 KB (x bf16, then LN(x))
    __shared__ __align__(16) short wbuf[16384];     // 32 KB: w1s[0:8192) w2s[8192:)
    __shared__ __align__(16) short sbuf[64][40];    // 5.1 KB hidden chunk
    __shared__ float red_s[64][4], red_s2[64][4];
    __shared__ float mu[64], rsd[64];
    __shared__ int   toks[64];

    short* w1s = wbuf;
    short* w2s = wbuf + 8192;

    int tid = threadIdx.x;
    int t0 = blockIdx.x * 64;
    int pr = blockIdx.x >> 1;
    const float* psr = g_para_state + pr * HH;

    if (tid < 64) toks[tid] = src[t0 + tid];
    __syncthreads();

    {   // ph1: coalesced x = emb+ps -> xn (bf16; thread owns dim tid)
        float psv = psr[tid];
        #pragma unroll 8
        for (int m = 0; m < 64; m++) {
            int tk = toks[m];
            float x = (tk ? emb[(size_t)tk * HH + tid] : 0.f) + psv;
            xn[m][tid] = f2b(x);
        }
    }
    __syncthreads();
    {   // ph2: LN stats from xn (bh8 reads, 2-way banks)
        int m = tid >> 2, q = tid & 3;
        float s = 0.f, s2 = 0.f;
        #pragma unroll
        for (int jb = 0; jb < 8; jb++) {
            bh8 v8 = *(const bh8*)&xn[m][q * 64 + jb * 8];
            #pragma unroll
            for (int e = 0; e < 8; e++) { float v = bs2f(v8[e]); s += v; s2 += v * v; }
        }
        red_s[m][q] = s; red_s2[m][q] = s2;
    }
    __syncthreads();
    if (tid < 64) {
        float s  = red_s [tid][0] + red_s [tid][1] + red_s [tid][2] + red_s [tid][3];
        float s2 = red_s2[tid][0] + red_s2[tid][1] + red_s2[tid][2] + red_s2[tid][3];
        float mean = s * (1.f / HH);
        float var  = s2 * (1.f / HH) - mean * mean;
        mu[tid] = mean; rsd[tid] = rsqrtf(var + 1e-6f);
    }
    __syncthreads();
    {   // ph3: normalize in place (thread owns dim tid)
        float g = lng[tid], bt = lnb[tid];
        #pragma unroll 8
        for (int m = 0; m < 64; m++) {
            float v = bs2f(xn[m][tid]);
            xn[m][tid] = f2b((v - mu[m]) * rsd[m] * g + bt);
        }
    }
    __syncthreads();

    int wv = tid >> 6, lane = tid & 63, quad = (lane >> 4) & 3, col = lane & 15;
    int sh = wv & 1, ch = wv >> 1;

    // A1 preload: 2 strips x 8 kk = 64 VGPRs, reused across all 32 chunks
    bh8 A1[2][8];
    #pragma unroll
    for (int si = 0; si < 2; si++)
        #pragma unroll
        for (int kk = 0; kk < 8; kk++)
            A1[si][kk] = *(const bh8*)&xn[(sh * 2 + si) * 16 + col][kk * 32 + quad * 8];

    f32x4 acc2[2][8];
    #pragma unroll
    for (int si = 0; si < 2; si++)
        #pragma unroll
        for (int j2 = 0; j2 < 8; j2++) acc2[si][j2] = (f32x4){0.f, 0.f, 0.f, 0.f};

    for (int c = 0; c < 32; c++) {
        // stage 32 KB: 8 batched loads then 8 ds_writes per thread
        {
            bh8 t1[4], t2[4];
            #pragma unroll
            for (int it = 0; it < 4; it++) {
                int g = it * 256 + tid;      // granule 0..1023
                t1[it] = *(const bh8*)(g_w1p + ((size_t)c * 1024 + g) * 8);
                t2[it] = *(const bh8*)(g_w2p + ((size_t)c * 1024 + g) * 8);
            }
            #pragma unroll
            for (int it = 0; it < 4; it++) {
                int g = it * 256 + tid;
                *(bh8*)(w1s + g * 8) = t1[it];
                *(bh8*)(w2s + g * 8) = t2[it];
            }
        }
        __syncthreads();

        // GEMM1: 8 B1 frags from LDS, 16 MFMAs
        f32x4 acc1[2];
        acc1[0] = (f32x4){0.f, 0.f, 0.f, 0.f};
        acc1[1] = (f32x4){0.f, 0.f, 0.f, 0.f};
        #pragma unroll
        for (int kk = 0; kk < 8; kk++) {
            bh8 bf = *(const bh8*)(w1s + ((kk * 2 + ch) * 64 + lane) * 8);
            acc1[0] = __builtin_amdgcn_mfma_f32_16x16x32_bf16(A1[0][kk], bf, acc1[0], 0, 0, 0);
            acc1[1] = __builtin_amdgcn_mfma_f32_16x16x32_bf16(A1[1][kk], bf, acc1[1], 0, 0, 0);
        }
        {   // bias + relu -> sbuf (A-layout for GEMM2)
            float bias = b1[c * 32 + ch * 16 + col];
            #pragma unroll
            for (int si = 0; si < 2; si++)
                #pragma unroll
                for (int r = 0; r < 4; r++) {
                    float v = acc1[si][r] + bias;
                    sbuf[(sh * 2 + si) * 16 + quad * 4 + r][ch * 16 + col] =
                        f2b(v > 0.f ? v : 0.f);
                }
        }
        __syncthreads();

        // GEMM2: chunk K=32 (one mfma per si,j2); 8 B2 frags from LDS
        #pragma unroll
        for (int si = 0; si < 2; si++) {
            bh8 a2 = *(const bh8*)&sbuf[(sh * 2 + si) * 16 + col][quad * 8];
            #pragma unroll
            for (int j2 = 0; j2 < 8; j2++) {
                bh8 bf = *(const bh8*)(w2s + ((ch * 8 + j2) * 64 + lane) * 8);
                acc2[si][j2] = __builtin_amdgcn_mfma_f32_16x16x32_bf16(a2, bf, acc2[si][j2], 0, 0, 0);
            }
        }
        __syncthreads();   // protect wbuf/sbuf before next stage
    }

    // Epilogue: + b2 + residual (recomputed fp32), mask, store
    #pragma unroll
    for (int j2 = 0; j2 < 8; j2++) {
        int n = (ch * 8 + j2) * 16 + col;
        float bias = b2v[n];
        float psv = psr[n];
        #pragma unroll
        for (int si = 0; si < 2; si++)
            #pragma unroll
            for (int r = 0; r < 4; r++) {
                int ml = (sh * 2 + si) * 16 + quad * 4 + r;
                int gt = t0 + ml;
                int tk = toks[ml];
                float x = (tk ? emb[(size_t)tk * HH + n] : 0.f) + psv;
                out_ctx[(size_t)gt * HH + n] = tk ? (acc2[si][j2][r] + bias + x) : 0.f;
            }
    }
}

// ---------------------------------------------------------------------------
extern "C" void kernel_launch(void* const* d_in, const int* in_sizes, int n_in,
                              void* d_out, int out_size, void* d_ws, size_t ws_size,
                              hipStream_t stream) {
    const int*   src     = (const int*)d_in[0];
    const int*   cluster = (const int*)d_in[1];
    const int*   edge    = (const int*)d_in[2];
    const float* emb     = (const float*)d_in[3];
    const float* p2c_wq  = (const float*)d_in[4];
    const float* p2c_wk  = (const float*)d_in[5];
    const float* p2c_wv  = (const float*)d_in[6];
    const float* p2c_wo  = (const float*)d_in[7];
    const float* c2p_wq  = (const float*)d_in[8];
    const float* c2p_wk  = (const float*)d_in[9];
    const float* c2p_wv  = (const float*)d_in[10];
    const float* c2p_wo  = (const float*)d_in[11];
    const float* w1      = (const float*)d_in[12];
    const float* b1      = (const float*)d_in[13];
    const float* w2      = (const float*)d_in[14];
    const float* b2p     = (const float*)d_in[15];
    const float* lng     = (const float*)d_in[16];
    const float* lnb     = (const float*)d_in[17];
    // d_in[18..20]: gat_iter=2, padding_idx=0, n_heads=8 (hard-coded)

    float* out      = (float*)d_out;
    float* out_ctx  = out + BB * PP * HH;                       // para_context
    float* out_clus = out + BB * PP * HH + BB * PP * TT * HH;   // cluster_state

    k_prep<<<dim3(704), dim3(256), 0, stream>>>(w1, w2,
        p2c_wq, p2c_wk, p2c_wv, p2c_wo, c2p_wq, c2p_wk, c2p_wv, c2p_wo,
        src, cluster, emb);
    k_gat<<<dim3(BB), dim3(1024), 0, stream>>>(edge, out, out_clus);
    k_ffn_mfma<<<dim3(256), dim3(256), 0, stream>>>(src, emb, b1, b2p, lng, lnb, out_ctx);
}

// Round 11
// 217.002 us; speedup vs baseline: 3.6078x; 1.2576x over previous
//
#include <hip/hip_runtime.h>
#include <hip/hip_bf16.h>

// Problem constants (fixed by setup_inputs):
#define BB 4
#define PP 32
#define TT 128
#define CC 16
#define TCC 64
#define HH 256
#define NHH 8
#define DD 32      // HH / NHH
#define FFF 1024
// gat_iter=2, padding_idx=0, n_heads=8 hard-coded.
// Inputs fp32, output fp32 (established; rounds 4-10 passed).

typedef __attribute__((ext_vector_type(8))) short bh8;    // 8 bf16 (4 VGPRs)
typedef __attribute__((ext_vector_type(4))) float f32x4;  // MFMA C/D

// Device-global scratch (fully rewritten before read every launch).
__device__ float g_para_feat [BB * PP * HH];
__device__ float g_clus_feat [BB * CC * HH];
__device__ float g_para_state[BB * PP * HH];
// FFN weights: ONE chunk-contiguous packed array, 32 chunks x 32 KB.
// chunk c bytes [c*32768, +32768): first 16 KB = W1 frags (granule f=kk*2+nt:
// B[k=kk*32+quad*8+j][n=c*32+nt*16+col]), second 16 KB = W2 frags (granule
// nt2: B[k=c*32+quad*8+j][n=nt2*16+col]). granule = 64 lanes x 16 B.
__device__ __align__(16) short g_wp[HH * FFF + FFF * HH];
// GAT weights: 8 matrices (p2c wq,wk,wv,wo, c2p wq,wk,wv,wo), each
// [kk(8)][nt(16)][lane(64)][j(8)]  (B-frag: B[k=kk*32+quad*8+j][n=nt*16+col])
__device__ __align__(16) short g_gatw[8 * HH * HH];

__device__ __forceinline__ short f2b(float f) {
    union { __hip_bfloat16 h; short s; } u;
    u.h = __float2bfloat16(f);
    return u.s;
}
__device__ __forceinline__ float bs2f(short s) {
    union { float f; unsigned u; } x;
    x.u = ((unsigned)(unsigned short)s) << 16;
    return x.f;
}
// Direct global->LDS DMA, 16 B/lane. gptr per-lane; lptr wave-uniform.
__device__ __forceinline__ void gll16(const void* g, void* l) {
    __builtin_amdgcn_global_load_lds(
        (const __attribute__((address_space(1))) void*)g,
        (__attribute__((address_space(3))) void*)l, 16, 0, 0);
}

// ---------------------------------------------------------------------------
// k_prep: [0,256) pack W1/W2 into g_wp; [256,448) encode feats; [448,704)
// pack GAT weights.
// ---------------------------------------------------------------------------
__global__ void __launch_bounds__(256) k_prep(
        const float* __restrict__ w1, const float* __restrict__ w2,
        const float* __restrict__ pq, const float* __restrict__ pk,
        const float* __restrict__ pv, const float* __restrict__ po,
        const float* __restrict__ cq, const float* __restrict__ ck,
        const float* __restrict__ cv, const float* __restrict__ co,
        const int* __restrict__ src, const int* __restrict__ cluster,
        const float* __restrict__ emb) {
    int tid = threadIdx.x;
    if (blockIdx.x < 256) {
        int idx = blockIdx.x * 256 + tid;     // granule 0..65535
        int c = idx >> 11, wi = idx & 2047;
        int lane = wi & 63, quad = (lane >> 4) & 3, col = lane & 15;
        short* dst = g_wp + (size_t)idx * 8;
        if (wi < 1024) {                      // W1
            int f = wi >> 6;                  // 0..15
            int nt = f & 1, kk = f >> 1;
            int n = c * 32 + nt * 16 + col;
            #pragma unroll
            for (int j = 0; j < 8; j++)
                dst[j] = f2b(w1[(kk * 32 + quad * 8 + j) * FFF + n]);
        } else {                              // W2
            int nt2 = (wi - 1024) >> 6;       // 0..15
            int n = nt2 * 16 + col;
            #pragma unroll
            for (int j = 0; j < 8; j++)
                dst[j] = f2b(w2[(c * 32 + quad * 8 + j) * HH + n]);
        }
    } else if (blockIdx.x < 448) {
        int bid = blockIdx.x - 256;
        __shared__ int stok[TT];
        if (bid < BB * PP) {
            if (tid < TT) stok[tid] = src[bid * TT + tid];
            __syncthreads();
            float acc = 0.f; int cnt = 0;
            #pragma unroll 8
            for (int i = 0; i < TT; i++) {
                int tk = stok[i];
                float e = emb[(size_t)tk * HH + tid];   // unconditional -> batches
                int nz = (tk != 0);
                cnt += nz; acc += nz ? e : 0.f;
            }
            g_para_feat[bid * HH + tid] = acc / fmaxf((float)cnt, 1.0f);
        } else {
            int cid = bid - BB * PP;
            if (tid < TCC) stok[tid] = cluster[cid * TCC + tid];
            __syncthreads();
            float acc = 0.f; int cnt = 0;
            #pragma unroll 8
            for (int i = 0; i < TCC; i++) {
                int tk = stok[i];
                float e = emb[(size_t)tk * HH + tid];
                int nz = (tk != 0);
                cnt += nz; acc += nz ? e : 0.f;
            }
            g_clus_feat[cid * HH + tid] = acc / fmaxf((float)cnt, 1.0f);
        }
    } else {
        int pid = blockIdx.x - 448;          // 0..255
        int mat = pid >> 5;                  // 0..7
        int gi = (pid & 31) * 256 + tid;     // granule 0..8191
        int lane = gi & 63, quad = (lane >> 4) & 3, col = lane & 15;
        int f = gi >> 6;                     // 0..127
        int nt = f & 15, kk = f >> 4;
        const float* ws = (mat == 0) ? pq : (mat == 1) ? pk : (mat == 2) ? pv :
                          (mat == 3) ? po : (mat == 4) ? cq : (mat == 5) ? ck :
                          (mat == 6) ? cv : co;
        short* dst = g_gatw + ((size_t)mat * 8192 + gi) * 8;
        int n = nt * 16 + col;
        #pragma unroll
        for (int j = 0; j < 8; j++)
            dst[j] = f2b(ws[(kk * 32 + quad * 8 + j) * HH + n]);
    }
}

// ---------------------------------------------------------------------------
// GAT layer, all-MFMA, batched weight loads. 1024 threads = 16 waves.
// ---------------------------------------------------------------------------
template<int NQ, int NK>
__device__ void gat_layer(int tid,
                          float (*__restrict__ qs)[264], short (*__restrict__ qsb)[264],
                          short (*__restrict__ kvb)[264],
                          const short* __restrict__ wm,
                          const int* __restrict__ msk, const int* __restrict__ has,
                          short (*__restrict__ s_q)[264],   // also reused as O
                          short (*__restrict__ s_k)[264],
                          short (*__restrict__ s_vT)[44],
                          short (*__restrict__ s_pb)[32][44]) {
    constexpr int MTQ = NQ / 16, MTK = NK / 16;
    int w = tid >> 6, lane = tid & 63, quad = (lane >> 4) & 3, col = lane & 15;

    // ---- Phase 1: q/k/v projections (Bf batch-loaded, then MFMA) ----
    constexpr int NI1 = ((MTQ + 2 * MTK) * 16) / 16;
    #pragma unroll
    for (int it = 0; it < NI1; it++) {
        int jid = it * 16 + w;
        int nt = jid & 15, t = jid >> 4;
        int mi, mt;
        if (t < MTQ)            { mi = 0; mt = t; }
        else if (t < MTQ + MTK) { mi = 1; mt = t - MTQ; }
        else                    { mi = 2; mt = t - MTQ - MTK; }
        const short (*Ab)[264] = (mi == 0) ? qsb : kvb;
        const short* bb = wm + mi * 65536;
        bh8 Bf[8];
        #pragma unroll
        for (int kk = 0; kk < 8; kk++)
            Bf[kk] = *(const bh8*)(bb + ((kk * 16 + nt) * 64 + lane) * 8);
        f32x4 acc = (f32x4){0.f, 0.f, 0.f, 0.f};
        #pragma unroll
        for (int kk = 0; kk < 8; kk++) {
            bh8 a = *(const bh8*)&Ab[mt * 16 + col][kk * 32 + quad * 8];
            acc = __builtin_amdgcn_mfma_f32_16x16x32_bf16(a, Bf[kk], acc, 0, 0, 0);
        }
        #pragma unroll
        for (int r = 0; r < 4; r++) {
            int row = mt * 16 + quad * 4 + r, n = nt * 16 + col;
            if (mi == 0)      s_q[row][n] = f2b(acc[r]);
            else if (mi == 1) s_k[row][n] = f2b(acc[r]);
            else              s_vT[n][row] = f2b(acc[r]);     // transposed
        }
    }
    if (NK == 16 && tid < 512) {  // zero vT pad rows [16,32)
        int d = tid >> 1, o = 16 + (tid & 1) * 8;
        #pragma unroll
        for (int j = 0; j < 8; j++) s_vT[d][o + j] = 0;
    }
    __syncthreads();

    // ---- Phase 2: scores = Q_h @ K_h^T (per head), mask, scale ----
    constexpr int NI2 = (8 * MTQ * MTK) / 16;
    #pragma unroll
    for (int it = 0; it < NI2; it++) {
        int jid = it * 16 + w;
        int h = jid & 7, rest = jid >> 3;
        int mt = rest % MTQ, nt = rest / MTQ;
        bh8 a  = *(const bh8*)&s_q[mt * 16 + col][h * 32 + quad * 8];
        bh8 bf = *(const bh8*)&s_k[nt * 16 + col][h * 32 + quad * 8];
        f32x4 acc = (f32x4){0.f, 0.f, 0.f, 0.f};
        acc = __builtin_amdgcn_mfma_f32_16x16x32_bf16(a, bf, acc, 0, 0, 0);
        #pragma unroll
        for (int r = 0; r < 4; r++) {
            int qrow = mt * 16 + quad * 4 + r, krow = nt * 16 + col;
            int bit = (msk[qrow] >> krow) & 1;
            s_pb[h][qrow][krow] = f2b(bit ? acc[r] * 0.17677669529663687f : -1e9f);
        }
    }
    __syncthreads();

    // ---- Phase 3: softmax per (qi, h), write normalized P (bf16, pad->0) ----
    if (tid < NQ * 8) {
        int qi = tid >> 3, h = tid & 7;
        float av[NK]; float mx = -1e30f;
        #pragma unroll
        for (int k = 0; k < NK; k++) { av[k] = bs2f(s_pb[h][qi][k]); mx = fmaxf(mx, av[k]); }
        float sm = 0.f;
        #pragma unroll
        for (int k = 0; k < NK; k++) { av[k] = __expf(av[k] - mx); sm += av[k]; }
        float inv = 1.f / sm;
        #pragma unroll
        for (int k = 0; k < NK; k++) s_pb[h][qi][k] = f2b(av[k] * inv);
        if (NK == 16) {
            #pragma unroll
            for (int k = 16; k < 32; k++) s_pb[h][qi][k] = 0;
        }
    }
    __syncthreads();

    // ---- Phase 4: O_h = P_h @ V_h  -> s_q reused as O ----
    constexpr int NI4 = (8 * MTQ * 2) / 16;
    #pragma unroll
    for (int it = 0; it < NI4; it++) {
        int jid = it * 16 + w;
        int h = jid & 7, rest = jid >> 3;
        int mt = rest % MTQ, nt2 = rest / MTQ;
        bh8 a  = *(const bh8*)&s_pb[h][mt * 16 + col][quad * 8];
        bh8 bf = *(const bh8*)&s_vT[h * 32 + nt2 * 16 + col][quad * 8];
        f32x4 acc = (f32x4){0.f, 0.f, 0.f, 0.f};
        acc = __builtin_amdgcn_mfma_f32_16x16x32_bf16(a, bf, acc, 0, 0, 0);
        #pragma unroll
        for (int r = 0; r < 4; r++)
            s_q[mt * 16 + quad * 4 + r][h * 32 + nt2 * 16 + col] = f2b(acc[r]);
    }
    __syncthreads();

    // ---- Phase 5: out = O @ wo ; qs += hasnb * out ; refresh bf16 mirror ----
    constexpr int NI5 = (MTQ * 16) / 16;
    #pragma unroll
    for (int it = 0; it < NI5; it++) {
        int jid = it * 16 + w;
        int nt = jid & 15, mt = jid >> 4;
        const short* bb = wm + 3 * 65536;
        bh8 Bf[8];
        #pragma unroll
        for (int kk = 0; kk < 8; kk++)
            Bf[kk] = *(const bh8*)(bb + ((kk * 16 + nt) * 64 + lane) * 8);
        f32x4 acc = (f32x4){0.f, 0.f, 0.f, 0.f};
        #pragma unroll
        for (int kk = 0; kk < 8; kk++) {
            bh8 a = *(const bh8*)&s_q[mt * 16 + col][kk * 32 + quad * 8];
            acc = __builtin_amdgcn_mfma_f32_16x16x32_bf16(a, Bf[kk], acc, 0, 0, 0);
        }
        #pragma unroll
        for (int r = 0; r < 4; r++) {
            int row = mt * 16 + quad * 4 + r, n = nt * 16 + col;
            float nv = qs[row][n] + (has[row] ? acc[r] : 0.f);
            qs[row][n] = nv;
            qsb[row][n] = f2b(nv);
        }
    }
    __syncthreads();
}

// ---------------------------------------------------------------------------
// k_gat: whole 5-layer chain, 1 block/batch, 1024 threads (16 waves).
// ---------------------------------------------------------------------------
__global__ void __launch_bounds__(1024, 4) k_gat(const int* __restrict__ edge,
                                                 float* __restrict__ out_ps,
                                                 float* __restrict__ out_cs) {
    __shared__ __align__(16) float s_ps [PP][264];
    __shared__ __align__(16) float s_cs [CC][264];
    __shared__ __align__(16) short s_psb[PP][264];
    __shared__ __align__(16) short s_csb[CC][264];
    __shared__ __align__(16) short s_q  [PP][264];
    __shared__ __align__(16) short s_k  [PP][264];
    __shared__ __align__(16) short s_vT [HH][44];
    __shared__ __align__(16) short s_pb [NHH][32][44];
    __shared__ int s_mskP[PP], s_hasP[PP], s_mskC[CC], s_hasC[CC];

    int b = blockIdx.x, tid = threadIdx.x;
    const int* eb = edge + b * PP * CC;

    #pragma unroll
    for (int rep = 0; rep < 8; rep++) {
        int idx = rep * 1024 + tid;
        float v = g_para_feat[b * PP * HH + idx];
        s_ps[idx >> 8][idx & 255] = v;
        s_psb[idx >> 8][idx & 255] = f2b(v);
    }
    #pragma unroll
    for (int rep = 0; rep < 4; rep++) {
        int idx = rep * 1024 + tid;
        float v = g_clus_feat[b * CC * HH + idx];
        s_cs[idx >> 8][idx & 255] = v;
        s_csb[idx >> 8][idx & 255] = f2b(v);
    }
    if (tid < PP) {
        int m = 0;
        #pragma unroll
        for (int k = 0; k < CC; k++) m |= (eb[tid * CC + k] > 0) << k;
        s_mskP[tid] = m; s_hasP[tid] = (m != 0);
    } else if (tid < PP + CC) {
        int ci = tid - PP, m = 0;
        #pragma unroll
        for (int p = 0; p < PP; p++) m |= (eb[p * CC + ci] > 0) << p;
        s_mskC[ci] = m; s_hasC[ci] = (m != 0);
    }
    __syncthreads();

    const short* wmp = g_gatw;                 // p2c set
    const short* wmc = g_gatw + 4 * 65536;     // c2p set

    gat_layer<PP, CC>(tid, s_ps, s_psb, s_csb, wmp, s_mskP, s_hasP, s_q, s_k, s_vT, s_pb);
    gat_layer<CC, PP>(tid, s_cs, s_csb, s_psb, wmc, s_mskC, s_hasC, s_q, s_k, s_vT, s_pb);
    gat_layer<PP, CC>(tid, s_ps, s_psb, s_csb, wmp, s_mskP, s_hasP, s_q, s_k, s_vT, s_pb);
    gat_layer<CC, PP>(tid, s_cs, s_csb, s_psb, wmc, s_mskC, s_hasC, s_q, s_k, s_vT, s_pb);
    gat_layer<PP, CC>(tid, s_ps, s_psb, s_csb, wmp, s_mskP, s_hasP, s_q, s_k, s_vT, s_pb);

    #pragma unroll
    for (int rep = 0; rep < 8; rep++) {
        int idx = rep * 1024 + tid;
        float v = s_ps[idx >> 8][idx & 255];
        out_ps[b * PP * HH + idx] = v;
        g_para_state[b * PP * HH + idx] = v;
    }
    #pragma unroll
    for (int rep = 0; rep < 4; rep++) {
        int idx = rep * 1024 + tid;
        out_cs[b * CC * HH + idx] = s_cs[idx >> 8][idx & 255];
    }
}

// ---------------------------------------------------------------------------
// FFN v7: 64 tokens/block, grid 256, 4 waves = (strip-pair sh, col-half ch).
// Chunk weights (32 KB) streamed via global_load_lds into a DOUBLE-BUFFER;
// prefetch of chunk c+1 overlaps GEMM2 of chunk c. LN folded into A1 preload;
// xr (bf16 x) persists for LN stats + epilogue residual. LDS ~108 KB.
// ---------------------------------------------------------------------------
__global__ void __launch_bounds__(256) k_ffn_mfma(
        const int* __restrict__ src, const float* __restrict__ emb,
        const float* __restrict__ b1, const float* __restrict__ b2v,
        const float* __restrict__ lng, const float* __restrict__ lnb,
        float* __restrict__ out_ctx) {
    __shared__ __align__(16) short xr[64][264];     // x = emb+ps, bf16 (33.8 KB)
    __shared__ __align__(16) short wbuf[2][16384];  // 64 KB double buffer
    __shared__ __align__(16) short sbuf[64][40];    // 5.1 KB hidden chunk
    __shared__ float red_s[64][4], red_s2[64][4];
    __shared__ float mu[64], rsd[64];
    __shared__ short sg[HH], sbt[HH];
    __shared__ int   toks[64];

    int tid = threadIdx.x;
    int t0 = blockIdx.x * 64;
    int pr = blockIdx.x >> 1;
    const float* psr = g_para_state + pr * HH;

    if (tid < 64) toks[tid] = src[t0 + tid];
    sg[tid]  = f2b(lng[tid]);
    sbt[tid] = f2b(lnb[tid]);
    __syncthreads();

    {   // ph1: coalesced x = emb+ps -> xr (unconditional loads -> batched)
        float psv = psr[tid];
        #pragma unroll 8
        for (int m = 0; m < 64; m++) {
            int tk = toks[m];
            float e = emb[(size_t)tk * HH + tid];
            xr[m][tid] = f2b((tk ? e : 0.f) + psv);
        }
    }
    __syncthreads();
    {   // ph2: LN stats from xr
        int m = tid >> 2, q = tid & 3;
        float s = 0.f, s2 = 0.f;
        #pragma unroll
        for (int jb = 0; jb < 8; jb++) {
            bh8 v8 = *(const bh8*)&xr[m][q * 64 + jb * 8];
            #pragma unroll
            for (int e = 0; e < 8; e++) { float v = bs2f(v8[e]); s += v; s2 += v * v; }
        }
        red_s[m][q] = s; red_s2[m][q] = s2;
    }
    __syncthreads();
    if (tid < 64) {
        float s  = red_s [tid][0] + red_s [tid][1] + red_s [tid][2] + red_s [tid][3];
        float s2 = red_s2[tid][0] + red_s2[tid][1] + red_s2[tid][2] + red_s2[tid][3];
        float mean = s * (1.f / HH);
        float var  = s2 * (1.f / HH) - mean * mean;
        mu[tid] = mean; rsd[tid] = rsqrtf(var + 1e-6f);
    }
    __syncthreads();

    int wv = tid >> 6, lane = tid & 63, quad = (lane >> 4) & 3, col = lane & 15;
    int sh = wv & 1, ch = wv >> 1;

    // A1 preload with LN applied on the fly (xr stays = raw x for epilogue)
    bh8 A1[2][8];
    #pragma unroll
    for (int si = 0; si < 2; si++) {
        int row = (sh * 2 + si) * 16 + col;
        float m_ = mu[row], r_ = rsd[row];
        #pragma unroll
        for (int kk = 0; kk < 8; kk++) {
            int d0 = kk * 32 + quad * 8;
            bh8 xv = *(const bh8*)&xr[row][d0];
            bh8 gv = *(const bh8*)&sg[d0];
            bh8 bv = *(const bh8*)&sbt[d0];
            bh8 o;
            #pragma unroll
            for (int e = 0; e < 8; e++)
                o[e] = f2b((bs2f(xv[e]) - m_) * r_ * bs2f(gv[e]) + bs2f(bv[e]));
            A1[si][kk] = o;
        }
    }

    // issue chunk 0 staging (8 x 1 KB per wave, direct to LDS, no VGPRs)
    {
        const char* gb = (const char*)g_wp + wv * 8192 + lane * 16;
        char* lb = (char*)&wbuf[0][0] + wv * 8192;
        #pragma unroll
        for (int i = 0; i < 8; i++)
            gll16(gb + i * 1024, lb + i * 1024);
    }

    f32x4 acc2[2][8];
    #pragma unroll
    for (int si = 0; si < 2; si++)
        #pragma unroll
        for (int j2 = 0; j2 < 8; j2++) acc2[si][j2] = (f32x4){0.f, 0.f, 0.f, 0.f};

    for (int c = 0; c < 32; c++) {
        int cur = c & 1;
        __syncthreads();   // chunk c data resident; wbuf[1-cur]/sbuf free

        // GEMM1: B1 frags from LDS
        const short* w1s = &wbuf[cur][0];
        f32x4 acc1[2];
        acc1[0] = (f32x4){0.f, 0.f, 0.f, 0.f};
        acc1[1] = (f32x4){0.f, 0.f, 0.f, 0.f};
        #pragma unroll
        for (int kk = 0; kk < 8; kk++) {
            bh8 bf = *(const bh8*)(w1s + ((kk * 2 + ch) * 64 + lane) * 8);
            acc1[0] = __builtin_amdgcn_mfma_f32_16x16x32_bf16(A1[0][kk], bf, acc1[0], 0, 0, 0);
            acc1[1] = __builtin_amdgcn_mfma_f32_16x16x32_bf16(A1[1][kk], bf, acc1[1], 0, 0, 0);
        }
        {   // bias + relu -> sbuf (A-layout for GEMM2)
            float bias = b1[c * 32 + ch * 16 + col];
            #pragma unroll
            for (int si = 0; si < 2; si++)
                #pragma unroll
                for (int r = 0; r < 4; r++) {
                    float v = acc1[si][r] + bias;
                    sbuf[(sh * 2 + si) * 16 + quad * 4 + r][ch * 16 + col] =
                        f2b(v > 0.f ? v : 0.f);
                }
        }
        __syncthreads();   // sbuf complete

        // prefetch chunk c+1 into the other buffer (overlaps GEMM2)
        if (c + 1 < 32) {
            const char* gb = (const char*)g_wp + (size_t)(c + 1) * 32768
                           + wv * 8192 + lane * 16;
            char* lb = (char*)&wbuf[1 - cur][0] + wv * 8192;
            #pragma unroll
            for (int i = 0; i < 8; i++)
                gll16(gb + i * 1024, lb + i * 1024);
        }

        // GEMM2: chunk K=32; B2 frags from LDS
        const short* w2s = &wbuf[cur][0] + 8192;
        #pragma unroll
        for (int si = 0; si < 2; si++) {
            bh8 a2 = *(const bh8*)&sbuf[(sh * 2 + si) * 16 + col][quad * 8];
            #pragma unroll
            for (int j2 = 0; j2 < 8; j2++) {
                bh8 bf = *(const bh8*)(w2s + ((ch * 8 + j2) * 64 + lane) * 8);
                acc2[si][j2] = __builtin_amdgcn_mfma_f32_16x16x32_bf16(a2, bf, acc2[si][j2], 0, 0, 0);
            }
        }
    }

    // Epilogue: + b2 + residual from xr (bf16 x, err ~1e-4), mask, store
    #pragma unroll
    for (int j2 = 0; j2 < 8; j2++) {
        int n = (ch * 8 + j2) * 16 + col;
        float bias = b2v[n];
        #pragma unroll
        for (int si = 0; si < 2; si++)
            #pragma unroll
            for (int r = 0; r < 4; r++) {
                int ml = (sh * 2 + si) * 16 + quad * 4 + r;
                int gt = t0 + ml;
                int tk = toks[ml];
                float x = bs2f(xr[ml][n]);
                out_ctx[(size_t)gt * HH + n] = tk ? (acc2[si][j2][r] + bias + x) : 0.f;
            }
    }
}

// ---------------------------------------------------------------------------
extern "C" void kernel_launch(void* const* d_in, const int* in_sizes, int n_in,
                              void* d_out, int out_size, void* d_ws, size_t ws_size,
                              hipStream_t stream) {
    const int*   src     = (const int*)d_in[0];
    const int*   cluster = (const int*)d_in[1];
    const int*   edge    = (const int*)d_in[2];
    const float* emb     = (const float*)d_in[3];
    const float* p2c_wq  = (const float*)d_in[4];
    const float* p2c_wk  = (const float*)d_in[5];
    const float* p2c_wv  = (const float*)d_in[6];
    const float* p2c_wo  = (const float*)d_in[7];
    const float* c2p_wq  = (const float*)d_in[8];
    const float* c2p_wk  = (const float*)d_in[9];
    const float* c2p_wv  = (const float*)d_in[10];
    const float* c2p_wo  = (const float*)d_in[11];
    const float* w1      = (const float*)d_in[12];
    const float* b1      = (const float*)d_in[13];
    const float* w2      = (const float*)d_in[14];
    const float* b2p     = (const float*)d_in[15];
    const float* lng     = (const float*)d_in[16];
    const float* lnb     = (const float*)d_in[17];
    // d_in[18..20]: gat_iter=2, padding_idx=0, n_heads=8 (hard-coded)

    float* out      = (float*)d_out;
    float* out_ctx  = out + BB * PP * HH;                       // para_context
    float* out_clus = out + BB * PP * HH + BB * PP * TT * HH;   // cluster_state

    k_prep<<<dim3(704), dim3(256), 0, stream>>>(w1, w2,
        p2c_wq, p2c_wk, p2c_wv, p2c_wo, c2p_wq, c2p_wk, c2p_wv, c2p_wo,
        src, cluster, emb);
    k_gat<<<dim3(BB), dim3(1024), 0, stream>>>(edge, out, out_clus);
    k_ffn_mfma<<<dim3(256), dim3(256), 0, stream>>>(src, emb, b1, b2p, lng, lnb, out_ctx);
}